// Round 8
// baseline (235.500 us; speedup 1.0000x reference)
//
#include <hip/hip_runtime.h>
#include <hip/hip_bf16.h>

typedef __hip_bfloat16 bf16;
__device__ __forceinline__ float b2f(bf16 v){ return __bfloat162float(v); }
__device__ __forceinline__ bf16 f2b(float v){ return __float2bfloat16(v); }

typedef __attribute__((ext_vector_type(8))) short frag_ab;   // 8 bf16 (4 VGPRs)
typedef __attribute__((ext_vector_type(4))) float frag_cd;   // 4 fp32 acc
typedef __attribute__((ext_vector_type(4))) short short4v;   // 8B

__device__ __forceinline__ frag_ab ld_frag_2xb64(const bf16* p){
  union { frag_ab f; short4v h[2]; } u;
  u.h[0] = *reinterpret_cast<const short4v*>(p);
  u.h[1] = *reinterpret_cast<const short4v*>(p+4);
  return u.f;
}

__device__ __forceinline__ void st_agent(float* p, float v){
  __hip_atomic_store(p, v, __ATOMIC_RELAXED, __HIP_MEMORY_SCOPE_AGENT);
}
__device__ __forceinline__ float ld_agent(const float* p){
  return __hip_atomic_load(p, __ATOMIC_RELAXED, __HIP_MEMORY_SCOPE_AGENT);
}

#define LLEN 3136
#define BATCH 2
#define NCHUNK 49
#define LC 64

// ---- dwconv3x3+gelu (blk<1024) | LayerNorm (1024..1135) | weight->bf16 prep (1136..1199) ----
__global__ void k_front(const float* __restrict__ x, const float* __restrict__ dww,
                        const float* __restrict__ dwb, bf16* __restrict__ tmp,
                        const float* nhw_, const float* nhb_, const float* nvw_,
                        const float* nvb_, bf16* __restrict__ xln,
                        float* __restrict__ YMEAN, int* __restrict__ ZCNT,
                        const float* __restrict__ h_inw, const float* __restrict__ v_inw,
                        const float* __restrict__ h_ow,  const float* __restrict__ v_ow,
                        const float* __restrict__ pww,   const float* __restrict__ h_xw,
                        const float* __restrict__ v_xw,
                        bf16* __restrict__ WBIN, bf16* __restrict__ WBOUT,
                        bf16* __restrict__ WBPW, bf16* __restrict__ WBX){
  int blk = blockIdx.x;
  int tid = threadIdx.x;
  if (blk < 1024){
    int bc = blk & 255;            // b*128 + c
    int seg = blk >> 8;
    int c = bc & 127;
    if (blk == 0){                 // re-zero sync state every graph replay
      if (tid < 256) YMEAN[tid] = 0.f;
      if (tid < 4)   ZCNT[tid] = 0;   // [0..1]=pw CNT, [2..3]=pw FLAG
    }
    const float* xp = x + (size_t)bc*LLEN;
    __shared__ float sxr[16][60];  // rows r0-1..r0+14 of this channel, cols zero-padded
    int r0 = seg*14;
    for (int idx = tid; idx < 16*56; idx += 256){
      int rr = idx/56, cc = idx%56;
      int gr = r0 - 1 + rr;
      sxr[rr][cc+1] = (gr >= 0 && gr < 56) ? xp[gr*56+cc] : 0.f;
    }
    if (tid < 16){ sxr[tid][0] = 0.f; sxr[tid][57] = 0.f; }
    float w[9];
    #pragma unroll
    for (int i=0;i<9;i++) w[i] = dww[c*9+i];
    float bias = dwb[c];
    __syncthreads();
    int pstart = seg * 784;
    for (int p = pstart + tid; p < pstart + 784; p += 256){
      int i = p/56, j = p%56;
      int li = i - r0;
      float acc = bias;
      #pragma unroll
      for (int a=0;a<3;a++)
        #pragma unroll
        for (int bb=0;bb<3;bb++)
          acc += w[a*3+bb] * sxr[li+a][j+bb];
      float g = 0.5f*acc*(1.0f + erff(acc*0.70710678118654752f));
      tmp[(size_t)bc*LLEN + p] = f2b(g);
    }
  } else if (blk < 1136){
    int idx2 = blk - 1024;         // 0..111
    int h = idx2 % 56, b = idx2 / 56;
    __shared__ float sx[128][57];
    __shared__ float smean[56], srstd[56];
    __shared__ float wh[128], bh[128], wv_[128], bv_[128];
    if (tid < 128){ wh[tid]=nhw_[tid]; bh[tid]=nhb_[tid];
                    wv_[tid]=nvw_[tid]; bv_[tid]=nvb_[tid]; }
    for (int idx = tid; idx < 128*56; idx += 256){
      int c = idx / 56, w = idx % 56;
      sx[c][w] = x[((size_t)(b*128+c))*LLEN + h*56 + w];
    }
    __syncthreads();
    if (tid < 56){
      float s=0.f, s2=0.f;
      for (int c=0;c<128;c++){ float v = sx[c][tid]; s+=v; s2+=v*v; }
      float m = s*(1.f/128.f);
      float var = s2*(1.f/128.f) - m*m;
      smean[tid]=m; srstd[tid]=rsqrtf(var+1e-5f);
    }
    __syncthreads();
    bf16* outh = xln;
    bf16* outv = xln + (size_t)BATCH*LLEN*128;
    for (int idx = tid; idx < 56*128; idx += 256){
      int w = idx >> 7, c = idx & 127;
      float v = (sx[c][w]-smean[w])*srstd[w];
      outh[((size_t)b*LLEN + h*56 + w)*128 + c] = f2b(v*wh[c]+bh[c]);
      outv[((size_t)b*LLEN + w*56 + h)*128 + c] = f2b(v*wv_[c]+bv_[c]);
    }
  } else {
    // weight prep: f32 -> bf16 once per launch. Each thread: 16 consecutive elems.
    int pblk = blk - 1136;         // 0..63
    int t16 = tid*16;
    if (pblk < 32){                // WBIN: [dir][512][128], 131072 elems
      int g = pblk*4096 + t16;
      int dir = g >> 16, off = g & 65535;
      const float* src = (dir ? v_inw : h_inw) + off;
      bf16* dst = WBIN + g;
      #pragma unroll
      for (int r=0;r<4;r++){
        float4 w4 = *reinterpret_cast<const float4*>(src + r*4);
        bf16 t4[4] = {f2b(w4.x), f2b(w4.y), f2b(w4.z), f2b(w4.w)};
        *reinterpret_cast<double*>(dst + r*4) = *reinterpret_cast<double*>(t4);
      }
    } else if (pblk < 48){         // WBOUT: [dir][128][256], 65536 elems
      int g = (pblk-32)*4096 + t16;
      int dir = g >> 15, off = g & 32767;
      const float* src = (dir ? v_ow : h_ow) + off;
      bf16* dst = WBOUT + g;
      #pragma unroll
      for (int r=0;r<4;r++){
        float4 w4 = *reinterpret_cast<const float4*>(src + r*4);
        bf16 t4[4] = {f2b(w4.x), f2b(w4.y), f2b(w4.z), f2b(w4.w)};
        *reinterpret_cast<double*>(dst + r*4) = *reinterpret_cast<double*>(t4);
      }
    } else if (pblk < 52){         // WBPW: [128][128], 16384 elems
      int g = (pblk-48)*4096 + t16;
      const float* src = pww + g;
      bf16* dst = WBPW + g;
      #pragma unroll
      for (int r=0;r<4;r++){
        float4 w4 = *reinterpret_cast<const float4*>(src + r*4);
        bf16 t4[4] = {f2b(w4.x), f2b(w4.y), f2b(w4.z), f2b(w4.w)};
        *reinterpret_cast<double*>(dst + r*4) = *reinterpret_cast<double*>(t4);
      }
    } else if (pblk < 58){         // WBX: [dir][48][256], rows>=40 zero, 24576 elems
      int g = (pblk-52)*4096 + t16;
      int dir = (g >= 12288) ? 1 : 0;
      int off = g - dir*12288;
      int rr = off >> 8, cc = off & 255;
      bf16* dst = WBX + g;
      if (rr < 40){
        const float* src = (dir ? v_xw : h_xw) + rr*256 + cc;
        #pragma unroll
        for (int r=0;r<4;r++){
          float4 w4 = *reinterpret_cast<const float4*>(src + r*4);
          bf16 t4[4] = {f2b(w4.x), f2b(w4.y), f2b(w4.z), f2b(w4.w)};
          *reinterpret_cast<double*>(dst + r*4) = *reinterpret_cast<double*>(t4);
        }
      } else {
        bf16 z4[4] = {f2b(0.f), f2b(0.f), f2b(0.f), f2b(0.f)};
        double zd = *reinterpret_cast<double*>(z4);
        #pragma unroll
        for (int r=0;r<4;r++) *reinterpret_cast<double*>(dst + r*4) = zd;
      }
    }
  }
}

// -------- in_proj GEMM: one 64x64 n-tile per block, grid (98,8,2) = 1568 blocks --------
__global__ void k_inproj(const bf16* __restrict__ xln, const bf16* __restrict__ WBIN,
                         bf16* __restrict__ XI, bf16* __restrict__ Z){
  int dir = blockIdx.z;
  const bf16* A = xln + (size_t)dir*BATCH*LLEN*128;
  const bf16* Wb = WBIN + (size_t)dir*512*128;
  int m0 = blockIdx.x*64;
  int n0 = blockIdx.y*64;
  __shared__ __align__(16) bf16 sA[64][136];
  __shared__ __align__(16) bf16 sW[64][136];
  int tid = threadIdx.x;
  #pragma unroll
  for (int r=0;r<4;r++){
    int idx = tid + r*256;
    int row = idx >> 4, c8 = (idx & 15)*8;
    *reinterpret_cast<float4*>(&sA[row][c8]) =
        *reinterpret_cast<const float4*>(&A[(size_t)(m0+row)*128 + c8]);
    *reinterpret_cast<float4*>(&sW[row][c8]) =
        *reinterpret_cast<const float4*>(&Wb[(size_t)(n0+row)*128 + c8]);
  }
  __syncthreads();
  int wv2 = tid >> 6, lane = tid & 63;
  int qd = lane >> 4, mr = lane & 15;
  bf16* dst = (n0 < 256) ? XI : Z;
  int nb = n0 & 255;
  size_t dslab = (size_t)dir*BATCH*LLEN*256;
  frag_cd acc[4] = {};
  #pragma unroll
  for (int k0=0;k0<128;k0+=32){
    frag_ab af = *reinterpret_cast<frag_ab*>(&sA[wv2*16+mr][k0+qd*8]);
    #pragma unroll
    for (int t=0;t<4;t++){
      frag_ab bfr = *reinterpret_cast<frag_ab*>(&sW[t*16+mr][k0+qd*8]);
      acc[t] = __builtin_amdgcn_mfma_f32_16x16x32_bf16(af, bfr, acc[t], 0, 0, 0);
    }
  }
  #pragma unroll
  for (int t=0;t<4;t++)
    #pragma unroll
    for (int r=0;r<4;r++){
      int row = m0 + wv2*16 + qd*4 + r;
      int col = nb + t*16 + mr;
      dst[dslab + (size_t)row*256 + col] = f2b(acc[t][r]);
    }
}

// ---- fused conv1d(k=4,causal)+silu + xproj (MFMA) -> XS2/DT2/B/C; 512 threads (8 waves) ----
// conv & dt loops row-split: 2 threads per channel, 32 rows each (halved serial chains).
__global__ void k_dbl(const bf16* __restrict__ XI,
                      const float* hcw, const float* hcb, const float* vcw, const float* vcb,
                      const bf16* __restrict__ WBX,
                      const float* hdw, const float* vdw, const float* hdb, const float* vdb,
                      bf16* __restrict__ XS2, bf16* __restrict__ DT2,
                      float* __restrict__ Bf, float* __restrict__ Cf){
  int m0 = blockIdx.x*64;                      // 196 tiles
  int bd = m0 / LLEN;
  int l0m = m0 % LLEN;
  int dirq = bd >> 1;
  const bf16* XId = XI + (size_t)bd*LLEN*256;
  const bf16* Wb = WBX + (size_t)dirq*48*256;
  const float* cw = dirq ? vcw : hcw;
  const float* cb = dirq ? vcb : hcb;
  __shared__ __align__(16) bf16 sA[67][264];   // rows = XI[l0m-3 .. l0m+63]; conv overwrites rows 0..63
  __shared__ __align__(16) bf16 sW[48][264];   // rows 40..47 zero (prepped)
  __shared__ float sdbl[64][49];
  int tid = threadIdx.x;                       // 0..511
  for (int idx = tid; idx < 67*32; idx += 512){
    int row = idx >> 5, c8 = (idx & 31)*8;
    int l = l0m - 3 + row;
    float4 v = make_float4(0.f,0.f,0.f,0.f);
    if (l >= 0) v = *reinterpret_cast<const float4*>(&XId[(size_t)l*256 + c8]);
    *reinterpret_cast<float4*>(&sA[row][c8]) = v;
  }
  #pragma unroll
  for (int r=0;r<3;r++){
    int idx = tid + r*512;                     // 1536 = 48*32 chunks of 8
    int row = idx >> 5, c8 = (idx & 31)*8;
    *reinterpret_cast<float4*>(&sW[row][c8]) =
        *reinterpret_cast<const float4*>(&Wb[(size_t)row*256 + c8]);
  }
  __syncthreads();
  {
    int c = tid & 255;
    int half = tid >> 8;                       // 0: rows 0..31, 1: rows 32..63
    int j0 = half << 5;
    float w0=cw[c*4], w1=cw[c*4+1], w2=cw[c*4+2], w3=cw[c*4+3];
    float cbias = cb[c];
    size_t x2base = ((size_t)bd*16 + (c>>4))*LLEN + l0m + j0;
    int c16 = c & 15;
    float xm3 = b2f(sA[j0][c]), xm2 = b2f(sA[j0+1][c]), xm1 = b2f(sA[j0+2][c]);
    bf16 d0, d1, d2;                            // half=1 defers rows 32..34 (read by half=0 as inputs)
    #pragma unroll
    for (int jj=0;jj<32;jj++){
      float x0 = b2f(sA[j0+jj+3][c]);
      float acc = cbias + w0*xm3 + w1*xm2 + w2*xm1 + w3*x0;
      float s = acc / (1.f + __expf(-acc));
      bf16 sv = f2b(s);
      if (half){
        if (jj==0) d0=sv; else if (jj==1) d1=sv; else if (jj==2) d2=sv;
        else sA[j0+jj][c] = sv;
      } else {
        sA[j0+jj][c] = sv;
      }
      XS2[(x2base + jj)*16 + c16] = sv;
      xm3=xm2; xm2=xm1; xm1=x0;
    }
    __syncthreads();
    if (half){ sA[j0][c]=d0; sA[j0+1][c]=d1; sA[j0+2][c]=d2; }
  }
  __syncthreads();
  if (tid < 256){
    int wv2 = tid >> 6, lane = tid & 63;
    int qd = lane >> 4, mr = lane & 15;
    frag_cd acc[3] = {};
    #pragma unroll
    for (int k0=0;k0<256;k0+=32){
      frag_ab af = *reinterpret_cast<frag_ab*>(&sA[wv2*16+mr][k0+qd*8]);
      #pragma unroll
      for (int t=0;t<3;t++){
        frag_ab bfr = *reinterpret_cast<frag_ab*>(&sW[t*16+mr][k0+qd*8]);
        acc[t] = __builtin_amdgcn_mfma_f32_16x16x32_bf16(af, bfr, acc[t], 0, 0, 0);
      }
    }
    #pragma unroll
    for (int t=0;t<3;t++)
      #pragma unroll
      for (int r=0;r<4;r++){
        int col = t*16 + mr;
        if (col < 40) sdbl[wv2*16 + qd*4 + r][col] = acc[t][r];
      }
  }
  __syncthreads();
  {
    const float* dtw = dirq ? vdw : hdw;
    const float* dtb = dirq ? vdb : hdb;
    int c = tid & 255;
    int half = tid >> 8;
    int j0 = half << 5;
    float w8[8];
    #pragma unroll
    for (int r=0;r<8;r++) w8[r] = dtw[c*8+r];
    float biasv = dtb[c];
    size_t d2base = ((size_t)bd*16 + (c>>4))*LLEN + l0m + j0;
    int c16 = c & 15;
    for (int rr=0; rr<32; rr++){
      int row = j0 + rr;
      float a = biasv;
      #pragma unroll
      for (int r=0;r<8;r++) a += sdbl[row][r]*w8[r];
      float sv = (a > 20.f) ? a : __logf(1.f + __expf(a));
      DT2[(d2base + rr)*16 + c16] = f2b(sv);
    }
  }
  #pragma unroll
  for (int r=0;r<4;r++){
    int idx = tid + r*512;                     // 2048 = 64 rows * 32 vals
    int row = idx >> 5, o = idx & 31;
    float v = sdbl[row][8+o];
    size_t rr = (size_t)(m0+row)*16;
    if (o < 16) Bf[rr + o] = v;
    else        Cf[rr + (o-16)] = v;
  }
}

// ---------------- scan pass 1: local chunk scan (plain stores, no cross-block sync) ----------------
__global__ void k_scan1(const bf16* __restrict__ DT2, const bf16* __restrict__ XS2,
                        const float* __restrict__ Bc, const float* hA, const float* vA,
                        float* __restrict__ Pbuf, float* __restrict__ Hbuf){
  int bd = blockIdx.z;           // dir*2+b
  int g  = blockIdx.y;           // channel group 0..15
  int ck = blockIdx.x;           // chunk 0..48
  int l0 = ck*LC;
  const float* Bd = Bc + (size_t)bd*LLEN*16;
  const float* Alog = (bd >> 1) ? vA : hA;
  int tid = threadIdx.x;
  int dl = tid >> 4, n = tid & 15;
  float A = -__expf(Alog[(g*16+dl)*16+n]);
  __shared__ float sdt[LC][16], sxs[LC][16], sB[LC][16];
  size_t base2 = (((size_t)bd*16 + g)*LLEN + l0)*16;
  #pragma unroll
  for (int r=0;r<4;r++){
    int idx = tid + r*256;
    sdt[idx>>4][idx&15] = b2f(DT2[base2 + idx]);
    sxs[idx>>4][idx&15] = b2f(XS2[base2 + idx]);
    (&sB[0][0])[idx] = Bd[(size_t)l0*16 + idx];
  }
  __syncthreads();
  float h = 0.f, P = 1.f;
  #pragma unroll 8
  for (int i=0;i<LC;i++){
    float a = sdt[i][dl];
    float u = sxs[i][dl];
    float dA = __expf(a * A);
    h = dA*h + (a*u)*sB[i][n];
    P *= dA;
  }
  size_t sidx = (((size_t)bd*16 + g)*NCHUNK + ck)*256 + tid;
  Pbuf[sidx] = P;
  Hbuf[sidx] = h;
}

// ---------------- pass 2: sequential combine, software-pipelined 7x7 (plain L2 loads) ----------------
__global__ void k_scan2(const float* __restrict__ Pbuf, float* __restrict__ Hbuf){
  int q = blockIdx.x;            // bd*16+g, 0..63
  int tid = threadIdx.x;
  size_t qb = (size_t)q*NCHUNK*256 + tid;
  float Pv[7], Hv[7];
  float carry = 0.f;
  #pragma unroll
  for (int j=0;j<7;j++){
    Pv[j] = Pbuf[qb + (size_t)j*256];
    Hv[j] = Hbuf[qb + (size_t)j*256];
  }
  #pragma unroll
  for (int b=0;b<7;b++){
    float Pn[7], Hn[7];
    if (b < 6){
      #pragma unroll
      for (int j=0;j<7;j++){
        Pn[j] = Pbuf[qb + (size_t)((b+1)*7+j)*256];
        Hn[j] = Hbuf[qb + (size_t)((b+1)*7+j)*256];
      }
    }
    #pragma unroll
    for (int j=0;j<7;j++){
      Hbuf[qb + (size_t)(b*7+j)*256] = carry;   // h_init for chunk b*7+j
      carry = Pv[j]*carry + Hv[j];
    }
    if (b < 6){
      #pragma unroll
      for (int j=0;j<7;j++){ Pv[j] = Pn[j]; Hv[j] = Hn[j]; }
    }
  }
}

// ---------------- pass 3: local scan from h_init, swizzled LDS reduce (bank-conflict-free) ----------------
__global__ void k_scan3(const bf16* __restrict__ DT2, const bf16* __restrict__ XS2,
                        const float* __restrict__ Bc, const float* __restrict__ Cc,
                        const float* hA, const float* vA,
                        const float* __restrict__ Hbuf, bf16* __restrict__ ys){
  int bd = blockIdx.z;
  int g  = blockIdx.y;
  int ck = blockIdx.x;
  int l0 = ck*LC;
  const float* Bd = Bc + (size_t)bd*LLEN*16;
  const float* Cd = Cc + (size_t)bd*LLEN*16;
  bf16* yd = ys + (size_t)bd*LLEN*256;
  const float* Alog = (bd >> 1) ? vA : hA;
  int tid = threadIdx.x;
  int dl = tid >> 4, n = tid & 15;
  float A = -__expf(Alog[(g*16+dl)*16+n]);
  __shared__ float sdt[LC][16], sxs[LC][16], sB[LC][16], sC[LC][16];
  __shared__ float sp2[16][272];   // swizzled: element (dl,n) at dl*17+n -> <=2-way banks
  size_t base2 = (((size_t)bd*16 + g)*LLEN + l0)*16;
  #pragma unroll
  for (int r=0;r<4;r++){
    int idx = tid + r*256;
    sdt[idx>>4][idx&15] = b2f(DT2[base2 + idx]);
    sxs[idx>>4][idx&15] = b2f(XS2[base2 + idx]);
    (&sB[0][0])[idx] = Bd[(size_t)l0*16 + idx];
    (&sC[0][0])[idx] = Cd[(size_t)l0*16 + idx];
  }
  size_t sidx = (((size_t)bd*16 + g)*NCHUNK + ck)*256 + tid;
  float h = Hbuf[sidx];
  __syncthreads();
  int swz = dl*17 + n;
  int i_local = tid >> 4;
  int c16 = tid & 15;
  int rbase = c16*17;
  for (int i0=0; i0<LC; i0+=16){
    #pragma unroll
    for (int ii=0;ii<16;ii++){
      int i = i0 + ii;
      float a = sdt[i][dl];
      float u = sxs[i][dl];
      float dA = __expf(a * A);
      h = dA*h + (a*u)*sB[i][n];
      sp2[ii][swz] = h * sC[i][n];
    }
    __syncthreads();
    const float* row = &sp2[i_local][rbase];
    float s = 0.f;
    #pragma unroll
    for (int k=0;k<16;k++) s += row[k];
    yd[(size_t)(l0+i0+i_local)*256 + g*16 + c16] = f2b(s);
    __syncthreads();
  }
}

// -------- out_proj GEMM: one 32x64 tile per block, grid (196,2,2) = 784 blocks --------
__global__ void k_outgemm(const bf16* __restrict__ ys, const bf16* __restrict__ XS2,
                          const bf16* __restrict__ Z, const float* __restrict__ hD,
                          const float* __restrict__ vD, const bf16* __restrict__ WBOUT,
                          bf16* __restrict__ OD){
  int dir = blockIdx.y;
  int n0 = blockIdx.z*64;
  size_t slab = (size_t)dir*BATCH*LLEN*256;
  const bf16* Wb = WBOUT + (size_t)dir*128*256;
  const float* Dw = dir ? vD : hD;
  bf16* od = OD + (size_t)dir*BATCH*LLEN*128;
  int m0 = blockIdx.x*32;
  int bd = dir*2 + m0/LLEN;
  int lbase = m0 % LLEN;
  __shared__ __align__(16) bf16 sA[32][264];
  __shared__ __align__(16) bf16 sW[64][264];
  int tid = threadIdx.x;
  #pragma unroll
  for (int r=0;r<4;r++){
    int idx = tid + r*256;
    int row = idx >> 5, c8 = (idx & 31)*8;
    size_t e = slab + (size_t)(m0+row)*256 + c8;
    size_t e2 = (((size_t)bd*16 + (c8>>4))*LLEN + lbase + row)*16 + (c8&15);
    bf16 yb[8], xb[8], zb[8], ob[8];
    *reinterpret_cast<float4*>(yb) = *reinterpret_cast<const float4*>(&ys[e]);
    *reinterpret_cast<float4*>(xb) = *reinterpret_cast<const float4*>(&XS2[e2]);
    *reinterpret_cast<float4*>(zb) = *reinterpret_cast<const float4*>(&Z[e]);
    #pragma unroll
    for (int j=0;j<8;j++){
      float Dv = Dw[c8 + j];
      float yv = b2f(yb[j]) + b2f(xb[j])*Dv;
      float zv = b2f(zb[j]);
      ob[j] = f2b(yv * (zv/(1.f+__expf(-zv))));
    }
    *reinterpret_cast<float4*>(&sA[row][c8]) = *reinterpret_cast<float4*>(ob);
  }
  #pragma unroll
  for (int r=0;r<8;r++){
    int idx = tid + r*256;                   // 2048 chunks of 8
    int row = idx >> 5, c8 = (idx & 31)*8;
    *reinterpret_cast<float4*>(&sW[row][c8]) =
        *reinterpret_cast<const float4*>(&Wb[(size_t)(n0+row)*256 + c8]);
  }
  __syncthreads();
  int wv2 = tid >> 6, lane = tid & 63;
  int qd = lane >> 4, mr = lane & 15;
  int msub = wv2 & 1, tpair = (wv2 >> 1)*2;
  frag_cd acc[2] = {};
  #pragma unroll
  for (int k0=0;k0<256;k0+=32){
    frag_ab af = *reinterpret_cast<frag_ab*>(&sA[msub*16+mr][k0+qd*8]);
    #pragma unroll
    for (int i=0;i<2;i++){
      frag_ab bfr = *reinterpret_cast<frag_ab*>(&sW[(tpair+i)*16+mr][k0+qd*8]);
      acc[i] = __builtin_amdgcn_mfma_f32_16x16x32_bf16(af, bfr, acc[i], 0, 0, 0);
    }
  }
  #pragma unroll
  for (int i=0;i<2;i++)
    #pragma unroll
    for (int r=0;r<4;r++){
      int row = m0 + msub*16 + qd*4 + r;
      int col = n0 + (tpair+i)*16 + mr;
      od[(size_t)row*128 + col] = f2b(acc[i][r]);
    }
}

// ---- pw conv (MFMA, bf16 weights) + combine + YMEAN + gate + final out; 32-wide p-tiles ----
__global__ void k_pwcomb(const bf16* __restrict__ tmp, const bf16* __restrict__ WBPW,
                         const float* __restrict__ pwb, const bf16* __restrict__ OD,
                         const float* __restrict__ x, float* __restrict__ out,
                         float* __restrict__ YMEAN, int* __restrict__ CNTPW,
                         int* __restrict__ FLAG, float* __restrict__ GATE,
                         const float* __restrict__ fc1, const float* __restrict__ fc2){
  int p0 = blockIdx.x * 32;       // 98 p-tiles
  int m0 = blockIdx.y * 64;       // 2 out-channel halves
  int b  = blockIdx.z;
  const bf16* T = tmp + (size_t)b*128*LLEN;
  const bf16* od0 = OD + (size_t)b*LLEN*128;
  const bf16* od1 = OD + (size_t)(BATCH + b)*LLEN*128;
  __shared__ __align__(16) bf16 sA[64][136];    // pww rows m0.., k=c (bf16)
  __shared__ __align__(16) bf16 sBt[32][132];   // [p][c] transposed tmp tile
  __shared__ float sOD[32][65];                 // [p][m] od0 + od1^T
  __shared__ float ym[128], s1g[32];
  __shared__ int slast;
  int tid = threadIdx.x;
  #pragma unroll
  for (int r=0;r<4;r++){
    int idx = tid + r*256;
    int row = idx >> 4, c8 = (idx & 15)*8;
    *reinterpret_cast<float4*>(&sA[row][c8]) =
        *reinterpret_cast<const float4*>(&WBPW[(size_t)(m0+row)*128 + c8]);
  }
  #pragma unroll
  for (int r=0;r<4;r++){
    int idx = tid + r*256;       // 1024 = 128 c * 8 p-chunks of 4
    int c = idx >> 3, p4 = (idx & 7)*4;
    union { double d; bf16 v[4]; } u;
    u.d = *reinterpret_cast<const double*>(&T[(size_t)c*LLEN + p0 + p4]);
    #pragma unroll
    for (int j=0;j<4;j++) sBt[p4+j][c] = u.v[j];
  }
  #pragma unroll
  for (int r=0;r<4;r++){
    int idx = tid + r*256;       // 1024 = 32 p-rows * 32 m-pairs
    int prow = idx >> 5, mp = (idx & 31)*2;
    int p = p0 + prow;
    int pi = p/56, pj = p%56;
    int pt = pj*56 + pi;
    bf16 a0[2], a1[2];
    *reinterpret_cast<float*>(a0) = *reinterpret_cast<const float*>(&od0[(size_t)p*128 + m0 + mp]);
    *reinterpret_cast<float*>(a1) = *reinterpret_cast<const float*>(&od1[(size_t)pt*128 + m0 + mp]);
    sOD[prow][mp]   = b2f(a0[0]) + b2f(a1[0]);
    sOD[prow][mp+1] = b2f(a0[1]) + b2f(a1[1]);
  }
  __syncthreads();
  int wv2 = tid >> 6, lane = tid & 63;
  int qd = lane >> 4, mr = lane & 15;
  frag_cd acc[2] = {};
  #pragma unroll
  for (int k0=0;k0<128;k0+=32){
    frag_ab af = *reinterpret_cast<frag_ab*>(&sA[wv2*16+mr][k0+qd*8]);
    #pragma unroll
    for (int t=0;t<2;t++){
      frag_ab bfr = ld_frag_2xb64(&sBt[t*16+mr][k0+qd*8]);
      acc[t] = __builtin_amdgcn_mfma_f32_16x16x32_bf16(af, bfr, acc[t], 0, 0, 0);
    }
  }
  // fused values stay in registers; YMEAN partials via device-scope (memory-side) atomics
  float vals[2][4];
  #pragma unroll
  for (int r=0;r<4;r++){
    int m = m0 + wv2*16 + qd*4 + r;
    float bias = pwb[m];
    float s = 0.f;
    #pragma unroll
    for (int t=0;t<2;t++){
      float val = acc[t][r] + bias + sOD[t*16+mr][m - m0];
      vals[t][r] = val;
      s += val;
    }
    s += __shfl_xor(s, 1, 16);
    s += __shfl_xor(s, 2, 16);
    s += __shfl_xor(s, 4, 16);
    s += __shfl_xor(s, 8, 16);
    if (mr == 0) atomicAdd(&YMEAN[b*128 + m], s);
  }
  // __syncthreads drains the atomics (vmcnt) for all threads; then count. NO device fence.
  __syncthreads();
  if (tid == 0) slast = (atomicAdd(&CNTPW[b], 1) == 2*98 - 1);
  __syncthreads();
  if (slast){
    if (tid < 128)
      ym[tid] = ld_agent(&YMEAN[b*128+tid]) * (1.f/(float)LLEN);
    __syncthreads();
    {
      int o = tid >> 3, part = tid & 7;   // 32 outputs x 8 partials
      float a = 0.f;
      #pragma unroll
      for (int k=0;k<16;k++) a += ym[part*16 + k] * fc1[o*128 + part*16 + k];
      a += __shfl_xor(a, 1, 8);
      a += __shfl_xor(a, 2, 8);
      a += __shfl_xor(a, 4, 8);
      if (part == 0) s1g[o] = fmaxf(a, 0.f);
    }
    __syncthreads();
    if (tid < 128){
      float a = 0.f;
      #pragma unroll
      for (int j=0;j<32;j++) a += s1g[j]*fc2[tid*32+j];
      st_agent(&GATE[b*128+tid], 1.f/(1.f+__expf(-a)));
    }
    __syncthreads();               // drains GATE sc stores for all threads
    if (tid == 0)
      __hip_atomic_store(&FLAG[b], 1, __ATOMIC_RELEASE, __HIP_MEMORY_SCOPE_AGENT);
  } else {
    if (tid == 0)
      while (__hip_atomic_load(&FLAG[b], __ATOMIC_ACQUIRE, __HIP_MEMORY_SCOPE_AGENT) == 0)
        __builtin_amdgcn_s_sleep(2);
  }
  __syncthreads();
  float g4[4];
  #pragma unroll
  for (int r=0;r<4;r++){
    int m = m0 + wv2*16 + qd*4 + r;
    g4[r] = ld_agent(&GATE[b*128+m]);
  }
  #pragma unroll
  for (int t=0;t<2;t++)
    #pragma unroll
    for (int r=0;r<4;r++){
      int m = m0 + wv2*16 + qd*4 + r;
      int p = p0 + t*16 + mr;
      size_t i = ((size_t)b*128 + m)*LLEN + p;
      out[i] = vals[t][r]*g4[r] + x[i];
    }
}

extern "C" void kernel_launch(void* const* d_in, const int* in_sizes, int n_in,
                              void* d_out, int out_size, void* d_ws, size_t ws_size,
                              hipStream_t stream) {
  const float* x      = (const float*)d_in[0];
  const float* nhw    = (const float*)d_in[1];
  const float* nhb    = (const float*)d_in[2];
  const float* nvw    = (const float*)d_in[3];
  const float* nvb    = (const float*)d_in[4];
  const float* dww    = (const float*)d_in[5];
  const float* dwb    = (const float*)d_in[6];
  const float* pww    = (const float*)d_in[7];
  const float* pwb    = (const float*)d_in[8];
  const float* h_inw  = (const float*)d_in[9];
  const float* h_cw   = (const float*)d_in[10];
  const float* h_cb   = (const float*)d_in[11];
  const float* h_xw   = (const float*)d_in[12];
  const float* h_dtw  = (const float*)d_in[13];
  const float* h_dtb  = (const float*)d_in[14];
  const float* h_Al   = (const float*)d_in[15];
  const float* h_D    = (const float*)d_in[16];
  const float* h_ow   = (const float*)d_in[17];
  const float* v_inw  = (const float*)d_in[18];
  const float* v_cw   = (const float*)d_in[19];
  const float* v_cb   = (const float*)d_in[20];
  const float* v_xw   = (const float*)d_in[21];
  const float* v_dtw  = (const float*)d_in[22];
  const float* v_dtb  = (const float*)d_in[23];
  const float* v_Al   = (const float*)d_in[24];
  const float* v_D    = (const float*)d_in[25];
  const float* v_ow   = (const float*)d_in[26];
  const float* fc1    = (const float*)d_in[27];
  const float* fc2    = (const float*)d_in[28];

  float* out = (float*)d_out;

  // bf16 weight staging buffers live in d_out (dead until k_pwcomb's final writes,
  // and WBIN/WBOUT/WBX are consumed strictly before k_pwcomb launches).
  bf16* WBIN  = (bf16*)((char*)d_out + 0);        // 262,144 B  [dir][512][128]
  bf16* WBOUT = (bf16*)((char*)d_out + 262144);   // 131,072 B  [dir][128][256]
  bf16* WBX   = (bf16*)((char*)d_out + 393216);   //  49,152 B  [dir][48][256] (rows>=40 zero)
                                                  // ends 442,368 << 12.8 MB

  // Workspace layout (bytes). Stream-ordered-safe aliases:
  //  DT2 at base+0 (XLN under it dead after k_inproj); OD overlays DT2 (dead after k_scan3)
  //  YS overlays XI (XI dead after k_dbl); Pbuf/Hbuf outside all aliases; sync state after Pbuf
  char* base = (char*)d_ws;
  bf16*  XLN   = (bf16*)(base + 1605632);     // 3,211,264 B
  bf16*  DT2   = (bf16*)(base + 0);           // 6,422,528 B  [overlays XLN region; scan layout]
  bf16*  OD    = (bf16*)(base + 0);           // 3,211,264 B  [alias DT2; live after k_scan3]
  bf16*  XI    = (bf16*)(base + 6422528);     // 6,422,528 B
  bf16*  YS    = (bf16*)(base + 6422528);     // 6,422,528 B  [alias XI]
  bf16*  Z     = (bf16*)(base + 12845056);    // 6,422,528 B
  bf16*  XS2   = (bf16*)(base + 19267584);    // 6,422,528 B  [scan layout]
  float* Bf    = (float*)(base + 25690112);   //   802,816 B
  float* Cf    = (float*)(base + 26492928);   //   802,816 B
  float* Hbuf  = (float*)(base + 27295744);   // 3,211,264 B
  float* YMEAN = (float*)(base + 30507008);   //     1,024 B
  bf16*  TMP   = (bf16*)(base + 30508032);    // 1,605,632 B  (ends 32,113,664)
  float* Pbuf  = (float*)(base + 32113664);   // 3,211,264 B  (ends 35,324,928)
  int*   ZCNT  = (int*)  (base + 35324928);   // 4 ints: [0..1] pw CNT, [2..3] FLAG
  float* GATE  = (float*)(base + 35325440);   // 256 floats (ends 35,326,464)
  bf16*  WBPW  = (bf16*) (base + 35326464);   //  32,768 B [128][128] (ends 35,359,232)
  int*   CNTPW = ZCNT;
  int*   FLAG  = ZCNT + 2;

  k_front<<<dim3(1024 + 56*BATCH + 64), dim3(256), 0, stream>>>(
      x, dww, dwb, TMP, nhw, nhb, nvw, nvb, XLN, YMEAN, ZCNT,
      h_inw, v_inw, h_ow, v_ow, pww, h_xw, v_xw, WBIN, WBOUT, WBPW, WBX);
  k_inproj<<<dim3(98,8,2), dim3(256), 0, stream>>>(XLN, WBIN, XI, Z);
  k_dbl<<<dim3(196), dim3(512), 0, stream>>>(XI, h_cw, h_cb, v_cw, v_cb,
                                             WBX, h_dtw, v_dtw, h_dtb, v_dtb,
                                             XS2, DT2, Bf, Cf);
  k_scan1<<<dim3(NCHUNK,16,4), dim3(256), 0, stream>>>(DT2, XS2, Bf, h_Al, v_Al, Pbuf, Hbuf);
  k_scan2<<<dim3(64), dim3(256), 0, stream>>>(Pbuf, Hbuf);
  k_scan3<<<dim3(NCHUNK,16,4), dim3(256), 0, stream>>>(DT2, XS2, Bf, Cf, h_Al, v_Al, Hbuf, YS);
  k_outgemm<<<dim3(196,2,2), dim3(256), 0, stream>>>(YS, XS2, Z, h_D, v_D, WBOUT, OD);
  k_pwcomb<<<dim3(98,2,BATCH), dim3(256), 0, stream>>>(TMP, WBPW, pwb, OD, x, out,
                                                       YMEAN, CNTPW, FLAG, GATE, fc1, fc2);
}

// Round 9
// 215.842 us; speedup vs baseline: 1.0911x; 1.0911x over previous
//
#include <hip/hip_runtime.h>
#include <hip/hip_bf16.h>

typedef __hip_bfloat16 bf16;
__device__ __forceinline__ float b2f(bf16 v){ return __bfloat162float(v); }
__device__ __forceinline__ bf16 f2b(float v){ return __float2bfloat16(v); }

typedef __attribute__((ext_vector_type(8))) short frag_ab;   // 8 bf16 (4 VGPRs)
typedef __attribute__((ext_vector_type(4))) float frag_cd;   // 4 fp32 acc
typedef __attribute__((ext_vector_type(4))) short short4v;   // 8B

__device__ __forceinline__ frag_ab ld_frag_2xb64(const bf16* p){
  union { frag_ab f; short4v h[2]; } u;
  u.h[0] = *reinterpret_cast<const short4v*>(p);
  u.h[1] = *reinterpret_cast<const short4v*>(p+4);
  return u.f;
}

#define LLEN 3136
#define BATCH 2
#define NCHUNK 49
#define LC 64

// ---- dwconv3x3+gelu + TSUM partial (blk<1024) | LayerNorm (1024..1135) | weight prep (1136..1199) ----
__global__ void k_front(const float* __restrict__ x, const float* __restrict__ dww,
                        const float* __restrict__ dwb, bf16* __restrict__ tmp,
                        const float* nhw_, const float* nhb_, const float* nvw_,
                        const float* nvb_, bf16* __restrict__ xln,
                        const float* __restrict__ h_inw, const float* __restrict__ v_inw,
                        const float* __restrict__ h_ow,  const float* __restrict__ v_ow,
                        const float* __restrict__ pww,   const float* __restrict__ h_xw,
                        const float* __restrict__ v_xw,
                        bf16* __restrict__ WBIN, bf16* __restrict__ WBOUT,
                        bf16* __restrict__ WBPW, bf16* __restrict__ WBX,
                        float* __restrict__ TSUMP){
  int blk = blockIdx.x;
  int tid = threadIdx.x;
  if (blk < 1024){
    int bc = blk & 255;            // b*128 + c
    int seg = blk >> 8;
    int c = bc & 127;
    const float* xp = x + (size_t)bc*LLEN;
    __shared__ float sxr[16][60];  // rows r0-1..r0+14 of this channel, cols zero-padded
    __shared__ float wsum[4];
    int r0 = seg*14;
    for (int idx = tid; idx < 16*56; idx += 256){
      int rr = idx/56, cc = idx%56;
      int gr = r0 - 1 + rr;
      sxr[rr][cc+1] = (gr >= 0 && gr < 56) ? xp[gr*56+cc] : 0.f;
    }
    if (tid < 16){ sxr[tid][0] = 0.f; sxr[tid][57] = 0.f; }
    float w[9];
    #pragma unroll
    for (int i=0;i<9;i++) w[i] = dww[c*9+i];
    float bias = dwb[c];
    __syncthreads();
    int pstart = seg * 784;
    float ts = 0.f;
    for (int p = pstart + tid; p < pstart + 784; p += 256){
      int i = p/56, j = p%56;
      int li = i - r0;
      float acc = bias;
      #pragma unroll
      for (int a=0;a<3;a++)
        #pragma unroll
        for (int bb=0;bb<3;bb++)
          acc += w[a*3+bb] * sxr[li+a][j+bb];
      float g = 0.5f*acc*(1.0f + erff(acc*0.70710678118654752f));
      bf16 gb = f2b(g);
      tmp[(size_t)bc*LLEN + p] = gb;
      ts += b2f(gb);               // bf16-rounded sum (matches what pwcomb's MFMA consumes)
    }
    // block reduce 256 lanes -> 1
    ts += __shfl_xor(ts, 1, 64);
    ts += __shfl_xor(ts, 2, 64);
    ts += __shfl_xor(ts, 4, 64);
    ts += __shfl_xor(ts, 8, 64);
    ts += __shfl_xor(ts, 16, 64);
    ts += __shfl_xor(ts, 32, 64);
    if ((tid & 63) == 0) wsum[tid >> 6] = ts;
    __syncthreads();
    if (tid == 0) TSUMP[seg*256 + bc] = wsum[0]+wsum[1]+wsum[2]+wsum[3];
  } else if (blk < 1136){
    int idx2 = blk - 1024;         // 0..111
    int h = idx2 % 56, b = idx2 / 56;
    __shared__ float sx[128][57];
    __shared__ float smean[56], srstd[56];
    __shared__ float wh[128], bh[128], wv_[128], bv_[128];
    if (tid < 128){ wh[tid]=nhw_[tid]; bh[tid]=nhb_[tid];
                    wv_[tid]=nvw_[tid]; bv_[tid]=nvb_[tid]; }
    for (int idx = tid; idx < 128*56; idx += 256){
      int c = idx / 56, w = idx % 56;
      sx[c][w] = x[((size_t)(b*128+c))*LLEN + h*56 + w];
    }
    __syncthreads();
    if (tid < 56){
      float s=0.f, s2=0.f;
      for (int c=0;c<128;c++){ float v = sx[c][tid]; s+=v; s2+=v*v; }
      float m = s*(1.f/128.f);
      float var = s2*(1.f/128.f) - m*m;
      smean[tid]=m; srstd[tid]=rsqrtf(var+1e-5f);
    }
    __syncthreads();
    bf16* outh = xln;
    bf16* outv = xln + (size_t)BATCH*LLEN*128;
    for (int idx = tid; idx < 56*128; idx += 256){
      int w = idx >> 7, c = idx & 127;
      float v = (sx[c][w]-smean[w])*srstd[w];
      outh[((size_t)b*LLEN + h*56 + w)*128 + c] = f2b(v*wh[c]+bh[c]);
      outv[((size_t)b*LLEN + w*56 + h)*128 + c] = f2b(v*wv_[c]+bv_[c]);
    }
  } else {
    // weight prep: f32 -> bf16 once per launch. Each thread: 16 consecutive elems.
    int pblk = blk - 1136;         // 0..63
    int t16 = tid*16;
    if (pblk < 32){                // WBIN: [dir][512][128], 131072 elems
      int g = pblk*4096 + t16;
      int dir = g >> 16, off = g & 65535;
      const float* src = (dir ? v_inw : h_inw) + off;
      bf16* dst = WBIN + g;
      #pragma unroll
      for (int r=0;r<4;r++){
        float4 w4 = *reinterpret_cast<const float4*>(src + r*4);
        bf16 t4[4] = {f2b(w4.x), f2b(w4.y), f2b(w4.z), f2b(w4.w)};
        *reinterpret_cast<double*>(dst + r*4) = *reinterpret_cast<double*>(t4);
      }
    } else if (pblk < 48){         // WBOUT: [dir][128][256], 65536 elems
      int g = (pblk-32)*4096 + t16;
      int dir = g >> 15, off = g & 32767;
      const float* src = (dir ? v_ow : h_ow) + off;
      bf16* dst = WBOUT + g;
      #pragma unroll
      for (int r=0;r<4;r++){
        float4 w4 = *reinterpret_cast<const float4*>(src + r*4);
        bf16 t4[4] = {f2b(w4.x), f2b(w4.y), f2b(w4.z), f2b(w4.w)};
        *reinterpret_cast<double*>(dst + r*4) = *reinterpret_cast<double*>(t4);
      }
    } else if (pblk < 52){         // WBPW: [128][128], 16384 elems
      int g = (pblk-48)*4096 + t16;
      const float* src = pww + g;
      bf16* dst = WBPW + g;
      #pragma unroll
      for (int r=0;r<4;r++){
        float4 w4 = *reinterpret_cast<const float4*>(src + r*4);
        bf16 t4[4] = {f2b(w4.x), f2b(w4.y), f2b(w4.z), f2b(w4.w)};
        *reinterpret_cast<double*>(dst + r*4) = *reinterpret_cast<double*>(t4);
      }
    } else if (pblk < 58){         // WBX: [dir][48][256], rows>=40 zero, 24576 elems
      int g = (pblk-52)*4096 + t16;
      int dir = (g >= 12288) ? 1 : 0;
      int off = g - dir*12288;
      int rr = off >> 8, cc = off & 255;
      bf16* dst = WBX + g;
      if (rr < 40){
        const float* src = (dir ? v_xw : h_xw) + rr*256 + cc;
        #pragma unroll
        for (int r=0;r<4;r++){
          float4 w4 = *reinterpret_cast<const float4*>(src + r*4);
          bf16 t4[4] = {f2b(w4.x), f2b(w4.y), f2b(w4.z), f2b(w4.w)};
          *reinterpret_cast<double*>(dst + r*4) = *reinterpret_cast<double*>(t4);
        }
      } else {
        bf16 z4[4] = {f2b(0.f), f2b(0.f), f2b(0.f), f2b(0.f)};
        double zd = *reinterpret_cast<double*>(z4);
        #pragma unroll
        for (int r=0;r<4;r++) *reinterpret_cast<double*>(dst + r*4) = zd;
      }
    }
  }
}

// ---------------- in_proj GEMM (MFMA bf16): 64-row tile, 2 n-tiles per block, bf16 weights ----------------
__global__ void k_inproj(const bf16* __restrict__ xln, const bf16* __restrict__ WBIN,
                         bf16* __restrict__ XI, bf16* __restrict__ Z){
  int dir = blockIdx.z;
  const bf16* A = xln + (size_t)dir*BATCH*LLEN*128;
  const bf16* Wb = WBIN + (size_t)dir*512*128;
  int m0 = blockIdx.x*64;
  int npair = blockIdx.y*128;     // covers n0 = npair, npair+64 (same XI/Z half)
  __shared__ __align__(16) bf16 sA[64][136];
  __shared__ __align__(16) bf16 sW[64][136];
  int tid = threadIdx.x;
  #pragma unroll
  for (int r=0;r<4;r++){
    int idx = tid + r*256;
    int row = idx >> 4, c8 = (idx & 15)*8;
    *reinterpret_cast<float4*>(&sA[row][c8]) =
        *reinterpret_cast<const float4*>(&A[(size_t)(m0+row)*128 + c8]);
  }
  int wv2 = tid >> 6, lane = tid & 63;
  int qd = lane >> 4, mr = lane & 15;
  bf16* dst = (npair < 256) ? XI : Z;
  int nbase0 = npair & 255;
  size_t dslab = (size_t)dir*BATCH*LLEN*256;
  #pragma unroll
  for (int nt=0; nt<2; nt++){
    int n0 = npair + nt*64;
    __syncthreads();
    #pragma unroll
    for (int r=0;r<4;r++){
      int idx = tid + r*256;
      int row = idx >> 4, c8 = (idx & 15)*8;
      *reinterpret_cast<float4*>(&sW[row][c8]) =
          *reinterpret_cast<const float4*>(&Wb[(size_t)(n0+row)*128 + c8]);
    }
    __syncthreads();
    frag_cd acc[4] = {};
    #pragma unroll
    for (int k0=0;k0<128;k0+=32){
      frag_ab af = *reinterpret_cast<frag_ab*>(&sA[wv2*16+mr][k0+qd*8]);
      #pragma unroll
      for (int t=0;t<4;t++){
        frag_ab bfr = *reinterpret_cast<frag_ab*>(&sW[t*16+mr][k0+qd*8]);
        acc[t] = __builtin_amdgcn_mfma_f32_16x16x32_bf16(af, bfr, acc[t], 0, 0, 0);
      }
    }
    int nb = nbase0 + nt*64;
    #pragma unroll
    for (int t=0;t<4;t++)
      #pragma unroll
      for (int r=0;r<4;r++){
        int row = m0 + wv2*16 + qd*4 + r;
        int col = nb + t*16 + mr;
        dst[dslab + (size_t)row*256 + col] = f2b(acc[t][r]);
      }
  }
}

// ---------------- fused conv1d(k=4,causal)+silu + xproj (MFMA), bf16 weights ----------------
__global__ void k_dbl(const bf16* __restrict__ XI,
                      const float* hcw, const float* hcb, const float* vcw, const float* vcb,
                      const bf16* __restrict__ WBX,
                      const float* hdw, const float* vdw, const float* hdb, const float* vdb,
                      bf16* __restrict__ XS2, bf16* __restrict__ DT2,
                      float* __restrict__ Bf, float* __restrict__ Cf){
  int m0 = blockIdx.x*64;                      // 196 tiles
  int bd = m0 / LLEN;
  int l0m = m0 % LLEN;
  int dirq = bd >> 1;
  const bf16* XId = XI + (size_t)bd*LLEN*256;
  const bf16* Wb = WBX + (size_t)dirq*48*256;
  const float* cw = dirq ? vcw : hcw;
  const float* cb = dirq ? vcb : hcb;
  __shared__ __align__(16) bf16 sA[67][264];   // rows = XI[l0m-3 .. l0m+63]; conv overwrites rows 0..63
  __shared__ __align__(16) bf16 sW[48][264];   // rows 40..47 zero (prepped)
  __shared__ float sdbl[64][49];
  int tid = threadIdx.x;
  for (int idx = tid; idx < 67*32; idx += 256){
    int row = idx >> 5, c8 = (idx & 31)*8;
    int l = l0m - 3 + row;
    float4 v = make_float4(0.f,0.f,0.f,0.f);
    if (l >= 0) v = *reinterpret_cast<const float4*>(&XId[(size_t)l*256 + c8]);
    *reinterpret_cast<float4*>(&sA[row][c8]) = v;
  }
  #pragma unroll
  for (int r=0;r<6;r++){
    int idx = tid + r*256;                     // 1536 = 48*32 chunks of 8
    int row = idx >> 5, c8 = (idx & 31)*8;
    *reinterpret_cast<float4*>(&sW[row][c8]) =
        *reinterpret_cast<const float4*>(&Wb[(size_t)row*256 + c8]);
  }
  __syncthreads();
  {
    float w0=cw[tid*4], w1=cw[tid*4+1], w2=cw[tid*4+2], w3=cw[tid*4+3];
    float cbias = cb[tid];
    size_t x2base = ((size_t)bd*16 + (tid>>4))*LLEN + l0m;
    int c16 = tid & 15;
    float xm3 = b2f(sA[0][tid]), xm2 = b2f(sA[1][tid]), xm1 = b2f(sA[2][tid]);
    #pragma unroll 4
    for (int j=0;j<64;j++){
      float x0 = b2f(sA[j+3][tid]);
      float acc = cbias + w0*xm3 + w1*xm2 + w2*xm1 + w3*x0;
      float s = acc / (1.f + __expf(-acc));
      bf16 sv = f2b(s);
      sA[j][tid] = sv;                         // row j no longer read (window advanced)
      XS2[(x2base + j)*16 + c16] = sv;
      xm3=xm2; xm2=xm1; xm1=x0;
    }
  }
  __syncthreads();
  int wv2 = tid >> 6, lane = tid & 63;
  int qd = lane >> 4, mr = lane & 15;
  frag_cd acc[3] = {};
  #pragma unroll
  for (int k0=0;k0<256;k0+=32){
    frag_ab af = *reinterpret_cast<frag_ab*>(&sA[wv2*16+mr][k0+qd*8]);
    #pragma unroll
    for (int t=0;t<3;t++){
      frag_ab bfr = *reinterpret_cast<frag_ab*>(&sW[t*16+mr][k0+qd*8]);
      acc[t] = __builtin_amdgcn_mfma_f32_16x16x32_bf16(af, bfr, acc[t], 0, 0, 0);
    }
  }
  #pragma unroll
  for (int t=0;t<3;t++)
    #pragma unroll
    for (int r=0;r<4;r++){
      int col = t*16 + mr;
      if (col < 40) sdbl[wv2*16 + qd*4 + r][col] = acc[t][r];
    }
  __syncthreads();
  const float* dtw = dirq ? vdw : hdw;
  const float* dtb = dirq ? vdb : hdb;
  float w8[8];
  #pragma unroll
  for (int r=0;r<8;r++) w8[r] = dtw[tid*8+r];
  float biasv = dtb[tid];
  size_t d2base = ((size_t)bd*16 + (tid>>4))*LLEN + l0m;
  int c16 = tid & 15;
  for (int row=0; row<64; row++){
    float a = biasv;
    #pragma unroll
    for (int r=0;r<8;r++) a += sdbl[row][r]*w8[r];
    float sv = (a > 20.f) ? a : __logf(1.f + __expf(a));
    DT2[(d2base + row)*16 + c16] = f2b(sv);
  }
  #pragma unroll
  for (int r=0;r<8;r++){
    int idx = tid + r*256;                     // 2048 = 64 rows * 32 vals
    int row = idx >> 5, o = idx & 31;
    float v = sdbl[row][8+o];
    size_t rr = (size_t)(m0+row)*16;
    if (o < 16) Bf[rr + o] = v;
    else        Cf[rr + (o-16)] = v;
  }
}

// ---------------- scan pass 1: local chunk scan (plain stores, no cross-block sync) ----------------
__global__ void k_scan1(const bf16* __restrict__ DT2, const bf16* __restrict__ XS2,
                        const float* __restrict__ Bc, const float* hA, const float* vA,
                        float* __restrict__ Pbuf, float* __restrict__ Hbuf){
  int bd = blockIdx.z;           // dir*2+b
  int g  = blockIdx.y;           // channel group 0..15
  int ck = blockIdx.x;           // chunk 0..48
  int l0 = ck*LC;
  const float* Bd = Bc + (size_t)bd*LLEN*16;
  const float* Alog = (bd >> 1) ? vA : hA;
  int tid = threadIdx.x;
  int dl = tid >> 4, n = tid & 15;
  float A = -__expf(Alog[(g*16+dl)*16+n]);
  __shared__ float sdt[LC][16], sxs[LC][16], sB[LC][16];
  size_t base2 = (((size_t)bd*16 + g)*LLEN + l0)*16;
  #pragma unroll
  for (int r=0;r<4;r++){
    int idx = tid + r*256;
    sdt[idx>>4][idx&15] = b2f(DT2[base2 + idx]);
    sxs[idx>>4][idx&15] = b2f(XS2[base2 + idx]);
    (&sB[0][0])[idx] = Bd[(size_t)l0*16 + idx];
  }
  __syncthreads();
  float h = 0.f, P = 1.f;
  #pragma unroll 8
  for (int i=0;i<LC;i++){
    float a = sdt[i][dl];
    float u = sxs[i][dl];
    float dA = __expf(a * A);
    h = dA*h + (a*u)*sB[i][n];
    P *= dA;
  }
  size_t sidx = (((size_t)bd*16 + g)*NCHUNK + ck)*256 + tid;
  Pbuf[sidx] = P;
  Hbuf[sidx] = h;
}

// ---------------- pass 2: sequential combine, software-pipelined 7x7 (plain L2 loads) ----------------
__global__ void k_scan2(const float* __restrict__ Pbuf, float* __restrict__ Hbuf){
  int q = blockIdx.x;            // bd*16+g, 0..63
  int tid = threadIdx.x;
  size_t qb = (size_t)q*NCHUNK*256 + tid;
  float Pv[7], Hv[7];
  float carry = 0.f;
  #pragma unroll
  for (int j=0;j<7;j++){
    Pv[j] = Pbuf[qb + (size_t)j*256];
    Hv[j] = Hbuf[qb + (size_t)j*256];
  }
  #pragma unroll
  for (int b=0;b<7;b++){
    float Pn[7], Hn[7];
    if (b < 6){
      #pragma unroll
      for (int j=0;j<7;j++){
        Pn[j] = Pbuf[qb + (size_t)((b+1)*7+j)*256];
        Hn[j] = Hbuf[qb + (size_t)((b+1)*7+j)*256];
      }
    }
    #pragma unroll
    for (int j=0;j<7;j++){
      Hbuf[qb + (size_t)(b*7+j)*256] = carry;   // h_init for chunk b*7+j
      carry = Pv[j]*carry + Hv[j];
    }
    if (b < 6){
      #pragma unroll
      for (int j=0;j<7;j++){ Pv[j] = Pn[j]; Hv[j] = Hn[j]; }
    }
  }
}

// ---------------- pass 3: local scan from h_init, swizzled LDS reduce (bank-conflict-free) ----------------
__global__ void k_scan3(const bf16* __restrict__ DT2, const bf16* __restrict__ XS2,
                        const float* __restrict__ Bc, const float* __restrict__ Cc,
                        const float* hA, const float* vA,
                        const float* __restrict__ Hbuf, bf16* __restrict__ ys){
  int bd = blockIdx.z;
  int g  = blockIdx.y;
  int ck = blockIdx.x;
  int l0 = ck*LC;
  const float* Bd = Bc + (size_t)bd*LLEN*16;
  const float* Cd = Cc + (size_t)bd*LLEN*16;
  bf16* yd = ys + (size_t)bd*LLEN*256;
  const float* Alog = (bd >> 1) ? vA : hA;
  int tid = threadIdx.x;
  int dl = tid >> 4, n = tid & 15;
  float A = -__expf(Alog[(g*16+dl)*16+n]);
  __shared__ float sdt[LC][16], sxs[LC][16], sB[LC][16], sC[LC][16];
  __shared__ float sp2[16][272];   // swizzled: element (dl,n) at dl*17+n -> <=2-way banks
  size_t base2 = (((size_t)bd*16 + g)*LLEN + l0)*16;
  #pragma unroll
  for (int r=0;r<4;r++){
    int idx = tid + r*256;
    sdt[idx>>4][idx&15] = b2f(DT2[base2 + idx]);
    sxs[idx>>4][idx&15] = b2f(XS2[base2 + idx]);
    (&sB[0][0])[idx] = Bd[(size_t)l0*16 + idx];
    (&sC[0][0])[idx] = Cd[(size_t)l0*16 + idx];
  }
  size_t sidx = (((size_t)bd*16 + g)*NCHUNK + ck)*256 + tid;
  float h = Hbuf[sidx];
  __syncthreads();
  int swz = dl*17 + n;
  int i_local = tid >> 4;
  int c16 = tid & 15;
  int rbase = c16*17;
  for (int i0=0; i0<LC; i0+=16){
    #pragma unroll
    for (int ii=0;ii<16;ii++){
      int i = i0 + ii;
      float a = sdt[i][dl];
      float u = sxs[i][dl];
      float dA = __expf(a * A);
      h = dA*h + (a*u)*sB[i][n];
      sp2[ii][swz] = h * sC[i][n];
    }
    __syncthreads();
    const float* row = &sp2[i_local][rbase];
    float s = 0.f;
    #pragma unroll
    for (int k=0;k<16;k++) s += row[k];
    yd[(size_t)(l0+i0+i_local)*256 + g*16 + c16] = f2b(s);
    __syncthreads();
  }
}

// ---- out_proj GEMM: 32-row tiles, both n-halves, bf16 weights; emits per-block OD column sums ----
__global__ void k_outgemm(const bf16* __restrict__ ys, const bf16* __restrict__ XS2,
                          const bf16* __restrict__ Z, const float* __restrict__ hD,
                          const float* __restrict__ vD, const bf16* __restrict__ WBOUT,
                          bf16* __restrict__ OD, float* __restrict__ OSUMP){
  int dir = blockIdx.y;
  size_t slab = (size_t)dir*BATCH*LLEN*256;
  const bf16* Wb = WBOUT + (size_t)dir*128*256;
  const float* Dw = dir ? vD : hD;
  bf16* od = OD + (size_t)dir*BATCH*LLEN*128;
  int m0 = blockIdx.x*32;
  int bd = dir*2 + m0/LLEN;
  int lbase = m0 % LLEN;
  __shared__ __align__(16) bf16 sA[32][264];
  __shared__ __align__(16) bf16 sW[64][264];
  __shared__ float scol[128];
  int tid = threadIdx.x;
  if (tid < 128) scol[tid] = 0.f;
  #pragma unroll
  for (int r=0;r<4;r++){
    int idx = tid + r*256;
    int row = idx >> 5, c8 = (idx & 31)*8;
    size_t e = slab + (size_t)(m0+row)*256 + c8;
    size_t e2 = (((size_t)bd*16 + (c8>>4))*LLEN + lbase + row)*16 + (c8&15);
    bf16 yb[8], xb[8], zb[8], ob[8];
    *reinterpret_cast<float4*>(yb) = *reinterpret_cast<const float4*>(&ys[e]);
    *reinterpret_cast<float4*>(xb) = *reinterpret_cast<const float4*>(&XS2[e2]);
    *reinterpret_cast<float4*>(zb) = *reinterpret_cast<const float4*>(&Z[e]);
    #pragma unroll
    for (int j=0;j<8;j++){
      float Dv = Dw[c8 + j];
      float yv = b2f(yb[j]) + b2f(xb[j])*Dv;
      float zv = b2f(zb[j]);
      ob[j] = f2b(yv * (zv/(1.f+__expf(-zv))));
    }
    *reinterpret_cast<float4*>(&sA[row][c8]) = *reinterpret_cast<float4*>(ob);
  }
  int wv2 = tid >> 6, lane = tid & 63;
  int qd = lane >> 4, mr = lane & 15;
  int msub = wv2 & 1, tpair = (wv2 >> 1)*2;
  #pragma unroll
  for (int nh=0; nh<2; nh++){
    int n0 = nh*64;
    __syncthreads();
    #pragma unroll
    for (int r=0;r<8;r++){
      int idx = tid + r*256;
      int row = idx >> 5, c8 = (idx & 31)*8;
      *reinterpret_cast<float4*>(&sW[row][c8]) =
          *reinterpret_cast<const float4*>(&Wb[(size_t)(n0+row)*256 + c8]);
    }
    __syncthreads();
    frag_cd acc[2] = {};
    #pragma unroll
    for (int k0=0;k0<256;k0+=32){
      frag_ab af = *reinterpret_cast<frag_ab*>(&sA[msub*16+mr][k0+qd*8]);
      #pragma unroll
      for (int i=0;i<2;i++){
        frag_ab bfr = *reinterpret_cast<frag_ab*>(&sW[(tpair+i)*16+mr][k0+qd*8]);
        acc[i] = __builtin_amdgcn_mfma_f32_16x16x32_bf16(af, bfr, acc[i], 0, 0, 0);
      }
    }
    #pragma unroll
    for (int i=0;i<2;i++){
      float cs = 0.f;
      #pragma unroll
      for (int r=0;r<4;r++){
        int row = m0 + msub*16 + qd*4 + r;
        int col = n0 + (tpair+i)*16 + mr;
        bf16 ov = f2b(acc[i][r]);
        od[(size_t)row*128 + col] = ov;
        cs += b2f(ov);                 // bf16-rounded (matches pwcomb's sOD consumption)
      }
      cs += __shfl_xor(cs, 16, 64);    // reduce over qd
      cs += __shfl_xor(cs, 32, 64);
      if (qd == 0) atomicAdd(&scol[n0 + (tpair+i)*16 + mr], cs);   // LDS atomic
    }
  }
  __syncthreads();
  if (tid < 128){
    int b = m0 / LLEN;
    int t = blockIdx.x % 98;
    OSUMP[(((size_t)(dir*2 + b)*98) + t)*128 + tid] = scol[tid];
  }
}

// ---- gate precompute: YMEAN analytically from TSUMP/OSUMP, then the MLP; 1 block per batch ----
__global__ void k_gate(const float* __restrict__ TSUMP, const float* __restrict__ OSUMP,
                       const bf16* __restrict__ WBPW, const float* __restrict__ pwb,
                       const float* __restrict__ fc1, const float* __restrict__ fc2,
                       float* __restrict__ GATE){
  int b = blockIdx.x;
  int tid = threadIdx.x;
  __shared__ float tsh[128], ym[128], s1g[32];
  if (tid < 128)
    tsh[tid] = TSUMP[0*256 + b*128 + tid] + TSUMP[1*256 + b*128 + tid]
             + TSUMP[2*256 + b*128 + tid] + TSUMP[3*256 + b*128 + tid];
  __syncthreads();
  if (tid < 128){
    float os = 0.f;
    for (int dir=0; dir<2; dir++)
      for (int t=0; t<98; t++)
        os += OSUMP[(((size_t)(dir*2 + b)*98) + t)*128 + tid];
    float pwpart = 0.f;
    #pragma unroll 8
    for (int c=0; c<128; c++)
      pwpart += b2f(WBPW[tid*128 + c]) * tsh[c];
    ym[tid] = (pwpart + os)*(1.f/(float)LLEN) + pwb[tid];
  }
  __syncthreads();
  {
    int o = tid >> 3, part = tid & 7;   // 32 outputs x 8 partials
    float a = 0.f;
    #pragma unroll
    for (int k=0;k<16;k++) a += ym[part*16 + k] * fc1[o*128 + part*16 + k];
    a += __shfl_xor(a, 1, 8);
    a += __shfl_xor(a, 2, 8);
    a += __shfl_xor(a, 4, 8);
    if (part == 0) s1g[o] = fmaxf(a, 0.f);
  }
  __syncthreads();
  if (tid < 128){
    float a = 0.f;
    #pragma unroll
    for (int j=0;j<32;j++) a += s1g[j]*fc2[tid*32+j];
    GATE[b*128+tid] = 1.f/(1.f+__expf(-a));
  }
}

// ---- pw conv (MFMA, bf16 weights) + combine + final out; gate precomputed, NO cross-block sync ----
__global__ void k_pwcomb(const bf16* __restrict__ tmp, const bf16* __restrict__ WBPW,
                         const float* __restrict__ pwb, const bf16* __restrict__ OD,
                         const float* __restrict__ x, float* __restrict__ out,
                         const float* __restrict__ GATE){
  int p0 = blockIdx.x * 64;       // 49 p-tiles
  int m0 = blockIdx.y * 64;       // 2 out-channel halves
  int b  = blockIdx.z;
  const bf16* T = tmp + (size_t)b*128*LLEN;
  const bf16* od0 = OD + (size_t)b*LLEN*128;
  const bf16* od1 = OD + (size_t)(BATCH + b)*LLEN*128;
  __shared__ __align__(16) bf16 sA[64][136];    // pww rows m0.., k=c (bf16)
  __shared__ __align__(16) bf16 sBt[64][132];   // [p][c] transposed tmp tile
  __shared__ float sOD[64][65];                 // [p][m] od0 + od1^T
  int tid = threadIdx.x;
  #pragma unroll
  for (int r=0;r<4;r++){
    int idx = tid + r*256;
    int row = idx >> 4, c8 = (idx & 15)*8;
    *reinterpret_cast<float4*>(&sA[row][c8]) =
        *reinterpret_cast<const float4*>(&WBPW[(size_t)(m0+row)*128 + c8]);
  }
  #pragma unroll
  for (int r=0;r<8;r++){
    int idx = tid + r*256;
    int c = idx >> 4, p4 = (idx & 15)*4;
    union { double d; bf16 v[4]; } u;
    u.d = *reinterpret_cast<const double*>(&T[(size_t)c*LLEN + p0 + p4]);
    #pragma unroll
    for (int j=0;j<4;j++) sBt[p4+j][c] = u.v[j];
  }
  #pragma unroll
  for (int r=0;r<8;r++){
    int idx = tid + r*256;       // 2048 = 64 p-rows * 32 m-pairs
    int prow = idx >> 5, mp = (idx & 31)*2;
    int p = p0 + prow;
    int pi = p/56, pj = p%56;
    int pt = pj*56 + pi;
    bf16 a0[2], a1[2];
    *reinterpret_cast<float*>(a0) = *reinterpret_cast<const float*>(&od0[(size_t)p*128 + m0 + mp]);
    *reinterpret_cast<float*>(a1) = *reinterpret_cast<const float*>(&od1[(size_t)pt*128 + m0 + mp]);
    sOD[prow][mp]   = b2f(a0[0]) + b2f(a1[0]);
    sOD[prow][mp+1] = b2f(a0[1]) + b2f(a1[1]);
  }
  __syncthreads();
  int wv2 = tid >> 6, lane = tid & 63;
  int qd = lane >> 4, mr = lane & 15;
  frag_cd acc[4] = {};
  #pragma unroll
  for (int k0=0;k0<128;k0+=32){
    frag_ab af = *reinterpret_cast<frag_ab*>(&sA[wv2*16+mr][k0+qd*8]);
    #pragma unroll
    for (int t=0;t<4;t++){
      frag_ab bfr = ld_frag_2xb64(&sBt[t*16+mr][k0+qd*8]);
      acc[t] = __builtin_amdgcn_mfma_f32_16x16x32_bf16(af, bfr, acc[t], 0, 0, 0);
    }
  }
  #pragma unroll
  for (int r=0;r<4;r++){
    int m = m0 + wv2*16 + qd*4 + r;
    float bias = pwb[m];
    float g = GATE[b*128 + m];
    #pragma unroll
    for (int t=0;t<4;t++){
      float val = acc[t][r] + bias + sOD[t*16+mr][m - m0];
      int p = p0 + t*16 + mr;
      size_t i = ((size_t)b*128 + m)*LLEN + p;
      out[i] = val*g + x[i];
    }
  }
}

extern "C" void kernel_launch(void* const* d_in, const int* in_sizes, int n_in,
                              void* d_out, int out_size, void* d_ws, size_t ws_size,
                              hipStream_t stream) {
  const float* x      = (const float*)d_in[0];
  const float* nhw    = (const float*)d_in[1];
  const float* nhb    = (const float*)d_in[2];
  const float* nvw    = (const float*)d_in[3];
  const float* nvb    = (const float*)d_in[4];
  const float* dww    = (const float*)d_in[5];
  const float* dwb    = (const float*)d_in[6];
  const float* pww    = (const float*)d_in[7];
  const float* pwb    = (const float*)d_in[8];
  const float* h_inw  = (const float*)d_in[9];
  const float* h_cw   = (const float*)d_in[10];
  const float* h_cb   = (const float*)d_in[11];
  const float* h_xw   = (const float*)d_in[12];
  const float* h_dtw  = (const float*)d_in[13];
  const float* h_dtb  = (const float*)d_in[14];
  const float* h_Al   = (const float*)d_in[15];
  const float* h_D    = (const float*)d_in[16];
  const float* h_ow   = (const float*)d_in[17];
  const float* v_inw  = (const float*)d_in[18];
  const float* v_cw   = (const float*)d_in[19];
  const float* v_cb   = (const float*)d_in[20];
  const float* v_xw   = (const float*)d_in[21];
  const float* v_dtw  = (const float*)d_in[22];
  const float* v_dtb  = (const float*)d_in[23];
  const float* v_Al   = (const float*)d_in[24];
  const float* v_D    = (const float*)d_in[25];
  const float* v_ow   = (const float*)d_in[26];
  const float* fc1    = (const float*)d_in[27];
  const float* fc2    = (const float*)d_in[28];

  float* out = (float*)d_out;

  // Staging that is fully consumed BEFORE k_pwcomb's out writes lives in d_out:
  bf16*  WBIN  = (bf16*) ((char*)d_out + 0);        // 262,144 B  [dir][512][128]
  bf16*  WBOUT = (bf16*) ((char*)d_out + 262144);   // 131,072 B  [dir][128][256]
  bf16*  WBX   = (bf16*) ((char*)d_out + 393216);   //  49,152 B  [dir][48][256]
  float* TSUMP = (float*)((char*)d_out + 442368);   //   4,096 B  [4 seg][256 bc]
  float* OSUMP = (float*)((char*)d_out + 446464);   // 200,704 B  [4 bd][98 t][128 m]
                                                    // ends 647,168 << 12.8 MB

  // Workspace layout (bytes). Stream-ordered-safe aliases:
  //  DT2 at base+0 (XLN under it dead after k_inproj); OD overlays DT2 (dead after k_scan3)
  //  YS overlays XI (XI dead after k_dbl); Pbuf/Hbuf outside all aliases
  char* base = (char*)d_ws;
  bf16*  XLN   = (bf16*)(base + 1605632);     // 3,211,264 B
  bf16*  DT2   = (bf16*)(base + 0);           // 6,422,528 B  [overlays XLN region; scan layout]
  bf16*  OD    = (bf16*)(base + 0);           // 3,211,264 B  [alias DT2; live after k_scan3]
  bf16*  XI    = (bf16*)(base + 6422528);     // 6,422,528 B
  bf16*  YS    = (bf16*)(base + 6422528);     // 6,422,528 B  [alias XI]
  bf16*  Z     = (bf16*)(base + 12845056);    // 6,422,528 B
  bf16*  XS2   = (bf16*)(base + 19267584);    // 6,422,528 B  [scan layout]
  float* Bf    = (float*)(base + 25690112);   //   802,816 B
  float* Cf    = (float*)(base + 26492928);   //   802,816 B
  float* Hbuf  = (float*)(base + 27295744);   // 3,211,264 B
  bf16*  TMP   = (bf16*)(base + 30508032);    // 1,605,632 B  (ends 32,113,664)
  float* Pbuf  = (float*)(base + 32113664);   // 3,211,264 B  (ends 35,324,928)
  bf16*  WBPW  = (bf16*) (base + 35326464);   //  32,768 B [128][128] (ends 35,359,232)
  float* GATE  = (float*)(base + 35359232);   //   1,024 B (ends 35,360,256)

  k_front<<<dim3(1024 + 56*BATCH + 64), dim3(256), 0, stream>>>(
      x, dww, dwb, TMP, nhw, nhb, nvw, nvb, XLN,
      h_inw, v_inw, h_ow, v_ow, pww, h_xw, v_xw, WBIN, WBOUT, WBPW, WBX, TSUMP);
  k_inproj<<<dim3(98,4,2), dim3(256), 0, stream>>>(XLN, WBIN, XI, Z);
  k_dbl<<<dim3(196), dim3(256), 0, stream>>>(XI, h_cw, h_cb, v_cw, v_cb,
                                             WBX, h_dtw, v_dtw, h_dtb, v_dtb,
                                             XS2, DT2, Bf, Cf);
  k_scan1<<<dim3(NCHUNK,16,4), dim3(256), 0, stream>>>(DT2, XS2, Bf, h_Al, v_Al, Pbuf, Hbuf);
  k_scan2<<<dim3(64), dim3(256), 0, stream>>>(Pbuf, Hbuf);
  k_scan3<<<dim3(NCHUNK,16,4), dim3(256), 0, stream>>>(DT2, XS2, Bf, Cf, h_Al, v_Al, Hbuf, YS);
  k_outgemm<<<dim3(196,2), dim3(256), 0, stream>>>(YS, XS2, Z, h_D, v_D, WBOUT, OD, OSUMP);
  k_gate<<<dim3(BATCH), dim3(256), 0, stream>>>(TSUMP, OSUMP, WBPW, pwb, fc1, fc2, GATE);
  k_pwcomb<<<dim3(49,2,BATCH), dim3(256), 0, stream>>>(TMP, WBPW, pwb, OD, x, out, GATE);
}

// Round 10
// 211.408 us; speedup vs baseline: 1.1140x; 1.0210x over previous
//
#include <hip/hip_runtime.h>
#include <hip/hip_bf16.h>

typedef __hip_bfloat16 bf16;
__device__ __forceinline__ float b2f(bf16 v){ return __bfloat162float(v); }
__device__ __forceinline__ bf16 f2b(float v){ return __float2bfloat16(v); }

typedef __attribute__((ext_vector_type(8))) short frag_ab;   // 8 bf16 (4 VGPRs)
typedef __attribute__((ext_vector_type(4))) float frag_cd;   // 4 fp32 acc
typedef __attribute__((ext_vector_type(4))) short short4v;   // 8B

__device__ __forceinline__ frag_ab ld_frag_2xb64(const bf16* p){
  union { frag_ab f; short4v h[2]; } u;
  u.h[0] = *reinterpret_cast<const short4v*>(p);
  u.h[1] = *reinterpret_cast<const short4v*>(p+4);
  return u.f;
}

#define LLEN 3136
#define BATCH 2
#define NCHUNK 49
#define LC 64

// ---- dwconv3x3+gelu + TSUM partial (blk<1024) | LayerNorm (1024..1135) | weight prep (1136..1199) ----
__global__ void k_front(const float* __restrict__ x, const float* __restrict__ dww,
                        const float* __restrict__ dwb, bf16* __restrict__ tmp,
                        const float* nhw_, const float* nhb_, const float* nvw_,
                        const float* nvb_, bf16* __restrict__ xln,
                        const float* __restrict__ h_inw, const float* __restrict__ v_inw,
                        const float* __restrict__ h_ow,  const float* __restrict__ v_ow,
                        const float* __restrict__ pww,   const float* __restrict__ h_xw,
                        const float* __restrict__ v_xw,
                        bf16* __restrict__ WBIN, bf16* __restrict__ WBOUT,
                        bf16* __restrict__ WBPW, bf16* __restrict__ WBX,
                        float* __restrict__ TSUMP){
  int blk = blockIdx.x;
  int tid = threadIdx.x;
  if (blk < 1024){
    int bc = blk & 255;            // b*128 + c
    int seg = blk >> 8;
    int c = bc & 127;
    const float* xp = x + (size_t)bc*LLEN;
    __shared__ float sxr[16][60];  // rows r0-1..r0+14 of this channel, cols zero-padded
    __shared__ float wsum[4];
    int r0 = seg*14;
    for (int idx = tid; idx < 16*56; idx += 256){
      int rr = idx/56, cc = idx%56;
      int gr = r0 - 1 + rr;
      sxr[rr][cc+1] = (gr >= 0 && gr < 56) ? xp[gr*56+cc] : 0.f;
    }
    if (tid < 16){ sxr[tid][0] = 0.f; sxr[tid][57] = 0.f; }
    float w[9];
    #pragma unroll
    for (int i=0;i<9;i++) w[i] = dww[c*9+i];
    float bias = dwb[c];
    __syncthreads();
    int pstart = seg * 784;
    float ts = 0.f;
    for (int p = pstart + tid; p < pstart + 784; p += 256){
      int i = p/56, j = p%56;
      int li = i - r0;
      float acc = bias;
      #pragma unroll
      for (int a=0;a<3;a++)
        #pragma unroll
        for (int bb=0;bb<3;bb++)
          acc += w[a*3+bb] * sxr[li+a][j+bb];
      float g = 0.5f*acc*(1.0f + erff(acc*0.70710678118654752f));
      bf16 gb = f2b(g);
      tmp[(size_t)bc*LLEN + p] = gb;
      ts += b2f(gb);               // bf16-rounded sum (matches what pwcomb's MFMA consumes)
    }
    // block reduce 256 lanes -> 1
    ts += __shfl_xor(ts, 1, 64);
    ts += __shfl_xor(ts, 2, 64);
    ts += __shfl_xor(ts, 4, 64);
    ts += __shfl_xor(ts, 8, 64);
    ts += __shfl_xor(ts, 16, 64);
    ts += __shfl_xor(ts, 32, 64);
    if ((tid & 63) == 0) wsum[tid >> 6] = ts;
    __syncthreads();
    if (tid == 0) TSUMP[seg*256 + bc] = wsum[0]+wsum[1]+wsum[2]+wsum[3];
  } else if (blk < 1136){
    int idx2 = blk - 1024;         // 0..111
    int h = idx2 % 56, b = idx2 / 56;
    __shared__ float sx[128][57];
    __shared__ float smean[56], srstd[56];
    __shared__ float wh[128], bh[128], wv_[128], bv_[128];
    if (tid < 128){ wh[tid]=nhw_[tid]; bh[tid]=nhb_[tid];
                    wv_[tid]=nvw_[tid]; bv_[tid]=nvb_[tid]; }
    for (int idx = tid; idx < 128*56; idx += 256){
      int c = idx / 56, w = idx % 56;
      sx[c][w] = x[((size_t)(b*128+c))*LLEN + h*56 + w];
    }
    __syncthreads();
    if (tid < 56){
      float s=0.f, s2=0.f;
      for (int c=0;c<128;c++){ float v = sx[c][tid]; s+=v; s2+=v*v; }
      float m = s*(1.f/128.f);
      float var = s2*(1.f/128.f) - m*m;
      smean[tid]=m; srstd[tid]=rsqrtf(var+1e-5f);
    }
    __syncthreads();
    bf16* outh = xln;
    bf16* outv = xln + (size_t)BATCH*LLEN*128;
    for (int idx = tid; idx < 56*128; idx += 256){
      int w = idx >> 7, c = idx & 127;
      float v = (sx[c][w]-smean[w])*srstd[w];
      outh[((size_t)b*LLEN + h*56 + w)*128 + c] = f2b(v*wh[c]+bh[c]);
      outv[((size_t)b*LLEN + w*56 + h)*128 + c] = f2b(v*wv_[c]+bv_[c]);
    }
  } else {
    // weight prep: f32 -> bf16 once per launch. Each thread: 16 consecutive elems.
    int pblk = blk - 1136;         // 0..63
    int t16 = tid*16;
    if (pblk < 32){                // WBIN: [dir][512][128], 131072 elems
      int g = pblk*4096 + t16;
      int dir = g >> 16, off = g & 65535;
      const float* src = (dir ? v_inw : h_inw) + off;
      bf16* dst = WBIN + g;
      #pragma unroll
      for (int r=0;r<4;r++){
        float4 w4 = *reinterpret_cast<const float4*>(src + r*4);
        bf16 t4[4] = {f2b(w4.x), f2b(w4.y), f2b(w4.z), f2b(w4.w)};
        *reinterpret_cast<double*>(dst + r*4) = *reinterpret_cast<double*>(t4);
      }
    } else if (pblk < 48){         // WBOUT: [dir][128][256], 65536 elems
      int g = (pblk-32)*4096 + t16;
      int dir = g >> 15, off = g & 32767;
      const float* src = (dir ? v_ow : h_ow) + off;
      bf16* dst = WBOUT + g;
      #pragma unroll
      for (int r=0;r<4;r++){
        float4 w4 = *reinterpret_cast<const float4*>(src + r*4);
        bf16 t4[4] = {f2b(w4.x), f2b(w4.y), f2b(w4.z), f2b(w4.w)};
        *reinterpret_cast<double*>(dst + r*4) = *reinterpret_cast<double*>(t4);
      }
    } else if (pblk < 52){         // WBPW: [128][128], 16384 elems
      int g = (pblk-48)*4096 + t16;
      const float* src = pww + g;
      bf16* dst = WBPW + g;
      #pragma unroll
      for (int r=0;r<4;r++){
        float4 w4 = *reinterpret_cast<const float4*>(src + r*4);
        bf16 t4[4] = {f2b(w4.x), f2b(w4.y), f2b(w4.z), f2b(w4.w)};
        *reinterpret_cast<double*>(dst + r*4) = *reinterpret_cast<double*>(t4);
      }
    } else if (pblk < 58){         // WBX: [dir][48][256], rows>=40 zero, 24576 elems
      int g = (pblk-52)*4096 + t16;
      int dir = (g >= 12288) ? 1 : 0;
      int off = g - dir*12288;
      int rr = off >> 8, cc = off & 255;
      bf16* dst = WBX + g;
      if (rr < 40){
        const float* src = (dir ? v_xw : h_xw) + rr*256 + cc;
        #pragma unroll
        for (int r=0;r<4;r++){
          float4 w4 = *reinterpret_cast<const float4*>(src + r*4);
          bf16 t4[4] = {f2b(w4.x), f2b(w4.y), f2b(w4.z), f2b(w4.w)};
          *reinterpret_cast<double*>(dst + r*4) = *reinterpret_cast<double*>(t4);
        }
      } else {
        bf16 z4[4] = {f2b(0.f), f2b(0.f), f2b(0.f), f2b(0.f)};
        double zd = *reinterpret_cast<double*>(z4);
        #pragma unroll
        for (int r=0;r<4;r++) *reinterpret_cast<double*>(dst + r*4) = zd;
      }
    }
  }
}

// ---------------- in_proj GEMM (MFMA bf16): 64-row tile, 2 n-tiles per block, bf16 weights ----------------
__global__ void k_inproj(const bf16* __restrict__ xln, const bf16* __restrict__ WBIN,
                         bf16* __restrict__ XI, bf16* __restrict__ Z){
  int dir = blockIdx.z;
  const bf16* A = xln + (size_t)dir*BATCH*LLEN*128;
  const bf16* Wb = WBIN + (size_t)dir*512*128;
  int m0 = blockIdx.x*64;
  int npair = blockIdx.y*128;     // covers n0 = npair, npair+64 (same XI/Z half)
  __shared__ __align__(16) bf16 sA[64][136];
  __shared__ __align__(16) bf16 sW[64][136];
  int tid = threadIdx.x;
  #pragma unroll
  for (int r=0;r<4;r++){
    int idx = tid + r*256;
    int row = idx >> 4, c8 = (idx & 15)*8;
    *reinterpret_cast<float4*>(&sA[row][c8]) =
        *reinterpret_cast<const float4*>(&A[(size_t)(m0+row)*128 + c8]);
  }
  int wv2 = tid >> 6, lane = tid & 63;
  int qd = lane >> 4, mr = lane & 15;
  bf16* dst = (npair < 256) ? XI : Z;
  int nbase0 = npair & 255;
  size_t dslab = (size_t)dir*BATCH*LLEN*256;
  #pragma unroll
  for (int nt=0; nt<2; nt++){
    int n0 = npair + nt*64;
    __syncthreads();
    #pragma unroll
    for (int r=0;r<4;r++){
      int idx = tid + r*256;
      int row = idx >> 4, c8 = (idx & 15)*8;
      *reinterpret_cast<float4*>(&sW[row][c8]) =
          *reinterpret_cast<const float4*>(&Wb[(size_t)(n0+row)*128 + c8]);
    }
    __syncthreads();
    frag_cd acc[4] = {};
    #pragma unroll
    for (int k0=0;k0<128;k0+=32){
      frag_ab af = *reinterpret_cast<frag_ab*>(&sA[wv2*16+mr][k0+qd*8]);
      #pragma unroll
      for (int t=0;t<4;t++){
        frag_ab bfr = *reinterpret_cast<frag_ab*>(&sW[t*16+mr][k0+qd*8]);
        acc[t] = __builtin_amdgcn_mfma_f32_16x16x32_bf16(af, bfr, acc[t], 0, 0, 0);
      }
    }
    int nb = nbase0 + nt*64;
    #pragma unroll
    for (int t=0;t<4;t++)
      #pragma unroll
      for (int r=0;r<4;r++){
        int row = m0 + wv2*16 + qd*4 + r;
        int col = nb + t*16 + mr;
        dst[dslab + (size_t)row*256 + col] = f2b(acc[t][r]);
      }
  }
}

// ---- fused conv1d(k=4,causal)+silu + xproj (MFMA): 32-row tiles, 392 blocks (own-halo) ----
__global__ void k_dbl(const bf16* __restrict__ XI,
                      const float* hcw, const float* hcb, const float* vcw, const float* vcb,
                      const bf16* __restrict__ WBX,
                      const float* hdw, const float* vdw, const float* hdb, const float* vdb,
                      bf16* __restrict__ XS2, bf16* __restrict__ DT2,
                      float* __restrict__ Bf, float* __restrict__ Cf){
  int m0 = blockIdx.x*32;                      // 392 tiles; 3136 % 32 == 0, never crosses bd
  int bd = m0 / LLEN;
  int l0m = m0 % LLEN;
  int dirq = bd >> 1;
  const bf16* XId = XI + (size_t)bd*LLEN*256;
  const bf16* Wb = WBX + (size_t)dirq*48*256;
  const float* cw = dirq ? vcw : hcw;
  const float* cb = dirq ? vcb : hcb;
  __shared__ __align__(16) bf16 sA[35][264];   // rows = XI[l0m-3 .. l0m+31]; conv overwrites rows 0..31
  __shared__ __align__(16) bf16 sW[48][264];   // rows 40..47 zero (prepped)
  __shared__ float sdbl[32][49];
  int tid = threadIdx.x;
  for (int idx = tid; idx < 35*32; idx += 256){
    int row = idx >> 5, c8 = (idx & 31)*8;
    int l = l0m - 3 + row;
    float4 v = make_float4(0.f,0.f,0.f,0.f);
    if (l >= 0) v = *reinterpret_cast<const float4*>(&XId[(size_t)l*256 + c8]);
    *reinterpret_cast<float4*>(&sA[row][c8]) = v;
  }
  #pragma unroll
  for (int r=0;r<6;r++){
    int idx = tid + r*256;                     // 1536 = 48*32 chunks of 8
    int row = idx >> 5, c8 = (idx & 31)*8;
    *reinterpret_cast<float4*>(&sW[row][c8]) =
        *reinterpret_cast<const float4*>(&Wb[(size_t)row*256 + c8]);
  }
  __syncthreads();
  {
    float w0=cw[tid*4], w1=cw[tid*4+1], w2=cw[tid*4+2], w3=cw[tid*4+3];
    float cbias = cb[tid];
    size_t x2base = ((size_t)bd*16 + (tid>>4))*LLEN + l0m;
    int c16 = tid & 15;
    float xm3 = b2f(sA[0][tid]), xm2 = b2f(sA[1][tid]), xm1 = b2f(sA[2][tid]);
    #pragma unroll 4
    for (int j=0;j<32;j++){
      float x0 = b2f(sA[j+3][tid]);
      float acc = cbias + w0*xm3 + w1*xm2 + w2*xm1 + w3*x0;
      float s = acc / (1.f + __expf(-acc));
      bf16 sv = f2b(s);
      sA[j][tid] = sv;                         // row j no longer read (window advanced)
      XS2[(x2base + j)*16 + c16] = sv;
      xm3=xm2; xm2=xm1; xm1=x0;
    }
  }
  __syncthreads();
  int wv2 = tid >> 6, lane = tid & 63;
  int qd = lane >> 4, mr = lane & 15;
  if (wv2 < 2){                                // 2 m-subtiles of 16 rows; waves 0-1 compute
    frag_cd acc[3] = {};
    #pragma unroll
    for (int k0=0;k0<256;k0+=32){
      frag_ab af = *reinterpret_cast<frag_ab*>(&sA[wv2*16+mr][k0+qd*8]);
      #pragma unroll
      for (int t=0;t<3;t++){
        frag_ab bfr = *reinterpret_cast<frag_ab*>(&sW[t*16+mr][k0+qd*8]);
        acc[t] = __builtin_amdgcn_mfma_f32_16x16x32_bf16(af, bfr, acc[t], 0, 0, 0);
      }
    }
    #pragma unroll
    for (int t=0;t<3;t++)
      #pragma unroll
      for (int r=0;r<4;r++){
        int col = t*16 + mr;
        if (col < 40) sdbl[wv2*16 + qd*4 + r][col] = acc[t][r];
      }
  }
  __syncthreads();
  const float* dtw = dirq ? vdw : hdw;
  const float* dtb = dirq ? vdb : hdb;
  float w8[8];
  #pragma unroll
  for (int r=0;r<8;r++) w8[r] = dtw[tid*8+r];
  float biasv = dtb[tid];
  size_t d2base = ((size_t)bd*16 + (tid>>4))*LLEN + l0m;
  int c16 = tid & 15;
  for (int row=0; row<32; row++){
    float a = biasv;
    #pragma unroll
    for (int r=0;r<8;r++) a += sdbl[row][r]*w8[r];
    float sv = (a > 20.f) ? a : __logf(1.f + __expf(a));
    DT2[(d2base + row)*16 + c16] = f2b(sv);
  }
  #pragma unroll
  for (int r=0;r<4;r++){
    int idx = tid + r*256;                     // 1024 = 32 rows * 32 vals
    int row = idx >> 5, o = idx & 31;
    float v = sdbl[row][8+o];
    size_t rr = (size_t)(m0+row)*16;
    if (o < 16) Bf[rr + o] = v;
    else        Cf[rr + (o-16)] = v;
  }
}

// ---------------- scan pass 1: local chunk scan (plain stores, no cross-block sync) ----------------
__global__ void k_scan1(const bf16* __restrict__ DT2, const bf16* __restrict__ XS2,
                        const float* __restrict__ Bc, const float* hA, const float* vA,
                        float* __restrict__ Pbuf, float* __restrict__ Hbuf){
  int bd = blockIdx.z;           // dir*2+b
  int g  = blockIdx.y;           // channel group 0..15
  int ck = blockIdx.x;           // chunk 0..48
  int l0 = ck*LC;
  const float* Bd = Bc + (size_t)bd*LLEN*16;
  const float* Alog = (bd >> 1) ? vA : hA;
  int tid = threadIdx.x;
  int dl = tid >> 4, n = tid & 15;
  float A = -__expf(Alog[(g*16+dl)*16+n]);
  __shared__ float sdt[LC][16], sxs[LC][16], sB[LC][16];
  size_t base2 = (((size_t)bd*16 + g)*LLEN + l0)*16;
  #pragma unroll
  for (int r=0;r<4;r++){
    int idx = tid + r*256;
    sdt[idx>>4][idx&15] = b2f(DT2[base2 + idx]);
    sxs[idx>>4][idx&15] = b2f(XS2[base2 + idx]);
    (&sB[0][0])[idx] = Bd[(size_t)l0*16 + idx];
  }
  __syncthreads();
  float h = 0.f, P = 1.f;
  #pragma unroll 8
  for (int i=0;i<LC;i++){
    float a = sdt[i][dl];
    float u = sxs[i][dl];
    float dA = __expf(a * A);
    h = dA*h + (a*u)*sB[i][n];
    P *= dA;
  }
  size_t sidx = (((size_t)bd*16 + g)*NCHUNK + ck)*256 + tid;
  Pbuf[sidx] = P;
  Hbuf[sidx] = h;
}

// ------- pass 3: redundant per-block prefix combine (scan2 fused) + local scan + LDS reduce -------
__global__ void k_scan3(const bf16* __restrict__ DT2, const bf16* __restrict__ XS2,
                        const float* __restrict__ Bc, const float* __restrict__ Cc,
                        const float* hA, const float* vA,
                        const float* __restrict__ Pbuf, const float* __restrict__ Hbuf,
                        bf16* __restrict__ ys){
  int bd = blockIdx.z;
  int g  = blockIdx.y;
  int ck = blockIdx.x;
  int l0 = ck*LC;
  const float* Bd = Bc + (size_t)bd*LLEN*16;
  const float* Cd = Cc + (size_t)bd*LLEN*16;
  bf16* yd = ys + (size_t)bd*LLEN*256;
  const float* Alog = (bd >> 1) ? vA : hA;
  int tid = threadIdx.x;
  int dl = tid >> 4, n = tid & 15;
  float A = -__expf(Alog[(g*16+dl)*16+n]);
  __shared__ float sdt[LC][16], sxs[LC][16], sB[LC][16], sC[LC][16];
  __shared__ float sp2[16][272];   // swizzled: element (dl,n) at dl*17+n -> <=2-way banks
  size_t base2 = (((size_t)bd*16 + g)*LLEN + l0)*16;
  #pragma unroll
  for (int r=0;r<4;r++){
    int idx = tid + r*256;
    sdt[idx>>4][idx&15] = b2f(DT2[base2 + idx]);
    sxs[idx>>4][idx&15] = b2f(XS2[base2 + idx]);
    (&sB[0][0])[idx] = Bd[(size_t)l0*16 + idx];
    (&sC[0][0])[idx] = Cd[(size_t)l0*16 + idx];
  }
  // prefix combine over chunks 0..ck-1 (same order as the old scan2; batched-8 for MLP)
  float h = 0.f;
  {
    size_t qbase = (size_t)(bd*16 + g)*NCHUNK*256 + tid;
    int k = 0;
    for (; k+8 <= ck; k += 8){
      float Pv[8], Hv[8];
      #pragma unroll
      for (int j=0;j<8;j++){
        Pv[j] = Pbuf[qbase + (size_t)(k+j)*256];
        Hv[j] = Hbuf[qbase + (size_t)(k+j)*256];
      }
      #pragma unroll
      for (int j=0;j<8;j++) h = Pv[j]*h + Hv[j];
    }
    for (; k < ck; ++k)
      h = Pbuf[qbase + (size_t)k*256]*h + Hbuf[qbase + (size_t)k*256];
  }
  __syncthreads();
  int swz = dl*17 + n;
  int i_local = tid >> 4;
  int c16 = tid & 15;
  int rbase = c16*17;
  for (int i0=0; i0<LC; i0+=16){
    #pragma unroll
    for (int ii=0;ii<16;ii++){
      int i = i0 + ii;
      float a = sdt[i][dl];
      float u = sxs[i][dl];
      float dA = __expf(a * A);
      h = dA*h + (a*u)*sB[i][n];
      sp2[ii][swz] = h * sC[i][n];
    }
    __syncthreads();
    const float* row = &sp2[i_local][rbase];
    float s = 0.f;
    #pragma unroll
    for (int k=0;k<16;k++) s += row[k];
    yd[(size_t)(l0+i0+i_local)*256 + g*16 + c16] = f2b(s);
    __syncthreads();
  }
}

// ---- out_proj GEMM: 32-row tiles, both n-halves, bf16 weights; emits per-block OD column sums ----
__global__ void k_outgemm(const bf16* __restrict__ ys, const bf16* __restrict__ XS2,
                          const bf16* __restrict__ Z, const float* __restrict__ hD,
                          const float* __restrict__ vD, const bf16* __restrict__ WBOUT,
                          bf16* __restrict__ OD, float* __restrict__ OSUMP){
  int dir = blockIdx.y;
  size_t slab = (size_t)dir*BATCH*LLEN*256;
  const bf16* Wb = WBOUT + (size_t)dir*128*256;
  const float* Dw = dir ? vD : hD;
  bf16* od = OD + (size_t)dir*BATCH*LLEN*128;
  int m0 = blockIdx.x*32;
  int bd = dir*2 + m0/LLEN;
  int lbase = m0 % LLEN;
  __shared__ __align__(16) bf16 sA[32][264];
  __shared__ __align__(16) bf16 sW[64][264];
  __shared__ float scol[128];
  int tid = threadIdx.x;
  if (tid < 128) scol[tid] = 0.f;
  #pragma unroll
  for (int r=0;r<4;r++){
    int idx = tid + r*256;
    int row = idx >> 5, c8 = (idx & 31)*8;
    size_t e = slab + (size_t)(m0+row)*256 + c8;
    size_t e2 = (((size_t)bd*16 + (c8>>4))*LLEN + lbase + row)*16 + (c8&15);
    bf16 yb[8], xb[8], zb[8], ob[8];
    *reinterpret_cast<float4*>(yb) = *reinterpret_cast<const float4*>(&ys[e]);
    *reinterpret_cast<float4*>(xb) = *reinterpret_cast<const float4*>(&XS2[e2]);
    *reinterpret_cast<float4*>(zb) = *reinterpret_cast<const float4*>(&Z[e]);
    #pragma unroll
    for (int j=0;j<8;j++){
      float Dv = Dw[c8 + j];
      float yv = b2f(yb[j]) + b2f(xb[j])*Dv;
      float zv = b2f(zb[j]);
      ob[j] = f2b(yv * (zv/(1.f+__expf(-zv))));
    }
    *reinterpret_cast<float4*>(&sA[row][c8]) = *reinterpret_cast<float4*>(ob);
  }
  int wv2 = tid >> 6, lane = tid & 63;
  int qd = lane >> 4, mr = lane & 15;
  int msub = wv2 & 1, tpair = (wv2 >> 1)*2;
  #pragma unroll
  for (int nh=0; nh<2; nh++){
    int n0 = nh*64;
    __syncthreads();
    #pragma unroll
    for (int r=0;r<8;r++){
      int idx = tid + r*256;
      int row = idx >> 5, c8 = (idx & 31)*8;
      *reinterpret_cast<float4*>(&sW[row][c8]) =
          *reinterpret_cast<const float4*>(&Wb[(size_t)(n0+row)*256 + c8]);
    }
    __syncthreads();
    frag_cd acc[2] = {};
    #pragma unroll
    for (int k0=0;k0<256;k0+=32){
      frag_ab af = *reinterpret_cast<frag_ab*>(&sA[msub*16+mr][k0+qd*8]);
      #pragma unroll
      for (int i=0;i<2;i++){
        frag_ab bfr = *reinterpret_cast<frag_ab*>(&sW[(tpair+i)*16+mr][k0+qd*8]);
        acc[i] = __builtin_amdgcn_mfma_f32_16x16x32_bf16(af, bfr, acc[i], 0, 0, 0);
      }
    }
    #pragma unroll
    for (int i=0;i<2;i++){
      float cs = 0.f;
      #pragma unroll
      for (int r=0;r<4;r++){
        int row = m0 + msub*16 + qd*4 + r;
        int col = n0 + (tpair+i)*16 + mr;
        bf16 ov = f2b(acc[i][r]);
        od[(size_t)row*128 + col] = ov;
        cs += b2f(ov);                 // bf16-rounded (matches pwcomb's sOD consumption)
      }
      cs += __shfl_xor(cs, 16, 64);    // reduce over qd
      cs += __shfl_xor(cs, 32, 64);
      if (qd == 0) atomicAdd(&scol[n0 + (tpair+i)*16 + mr], cs);   // LDS atomic
    }
  }
  __syncthreads();
  if (tid < 128){
    int b = m0 / LLEN;
    int t = blockIdx.x % 98;
    OSUMP[(((size_t)(dir*2 + b)*98) + t)*128 + tid] = scol[tid];
  }
}

// ---- gate precompute: YMEAN analytically from TSUMP/OSUMP, then the MLP; 1 block per batch ----
__global__ void k_gate(const float* __restrict__ TSUMP, const float* __restrict__ OSUMP,
                       const bf16* __restrict__ WBPW, const float* __restrict__ pwb,
                       const float* __restrict__ fc1, const float* __restrict__ fc2,
                       float* __restrict__ GATE){
  int b = blockIdx.x;
  int tid = threadIdx.x;
  __shared__ float tsh[128], ym[128], s1g[32];
  if (tid < 128)
    tsh[tid] = TSUMP[0*256 + b*128 + tid] + TSUMP[1*256 + b*128 + tid]
             + TSUMP[2*256 + b*128 + tid] + TSUMP[3*256 + b*128 + tid];
  __syncthreads();
  if (tid < 128){
    float os = 0.f;
    for (int dir=0; dir<2; dir++)
      for (int t=0; t<98; t++)
        os += OSUMP[(((size_t)(dir*2 + b)*98) + t)*128 + tid];
    float pwpart = 0.f;
    #pragma unroll 8
    for (int c=0; c<128; c++)
      pwpart += b2f(WBPW[tid*128 + c]) * tsh[c];
    ym[tid] = (pwpart + os)*(1.f/(float)LLEN) + pwb[tid];
  }
  __syncthreads();
  {
    int o = tid >> 3, part = tid & 7;   // 32 outputs x 8 partials
    float a = 0.f;
    #pragma unroll
    for (int k=0;k<16;k++) a += ym[part*16 + k] * fc1[o*128 + part*16 + k];
    a += __shfl_xor(a, 1, 8);
    a += __shfl_xor(a, 2, 8);
    a += __shfl_xor(a, 4, 8);
    if (part == 0) s1g[o] = fmaxf(a, 0.f);
  }
  __syncthreads();
  if (tid < 128){
    float a = 0.f;
    #pragma unroll
    for (int j=0;j<32;j++) a += s1g[j]*fc2[tid*32+j];
    GATE[b*128+tid] = 1.f/(1.f+__expf(-a));
  }
}

// ---- pw conv (MFMA, bf16 weights) + combine + final out; gate precomputed, NO cross-block sync ----
__global__ void k_pwcomb(const bf16* __restrict__ tmp, const bf16* __restrict__ WBPW,
                         const float* __restrict__ pwb, const bf16* __restrict__ OD,
                         const float* __restrict__ x, float* __restrict__ out,
                         const float* __restrict__ GATE){
  int p0 = blockIdx.x * 64;       // 49 p-tiles
  int m0 = blockIdx.y * 64;       // 2 out-channel halves
  int b  = blockIdx.z;
  const bf16* T = tmp + (size_t)b*128*LLEN;
  const bf16* od0 = OD + (size_t)b*LLEN*128;
  const bf16* od1 = OD + (size_t)(BATCH + b)*LLEN*128;
  __shared__ __align__(16) bf16 sA[64][136];    // pww rows m0.., k=c (bf16)
  __shared__ __align__(16) bf16 sBt[64][132];   // [p][c] transposed tmp tile
  __shared__ float sOD[64][65];                 // [p][m] od0 + od1^T
  int tid = threadIdx.x;
  #pragma unroll
  for (int r=0;r<4;r++){
    int idx = tid + r*256;
    int row = idx >> 4, c8 = (idx & 15)*8;
    *reinterpret_cast<float4*>(&sA[row][c8]) =
        *reinterpret_cast<const float4*>(&WBPW[(size_t)(m0+row)*128 + c8]);
  }
  #pragma unroll
  for (int r=0;r<8;r++){
    int idx = tid + r*256;
    int c = idx >> 4, p4 = (idx & 15)*4;
    union { double d; bf16 v[4]; } u;
    u.d = *reinterpret_cast<const double*>(&T[(size_t)c*LLEN + p0 + p4]);
    #pragma unroll
    for (int j=0;j<4;j++) sBt[p4+j][c] = u.v[j];
  }
  #pragma unroll
  for (int r=0;r<8;r++){
    int idx = tid + r*256;       // 2048 = 64 p-rows * 32 m-pairs
    int prow = idx >> 5, mp = (idx & 31)*2;
    int p = p0 + prow;
    int pi = p/56, pj = p%56;
    int pt = pj*56 + pi;
    bf16 a0[2], a1[2];
    *reinterpret_cast<float*>(a0) = *reinterpret_cast<const float*>(&od0[(size_t)p*128 + m0 + mp]);
    *reinterpret_cast<float*>(a1) = *reinterpret_cast<const float*>(&od1[(size_t)pt*128 + m0 + mp]);
    sOD[prow][mp]   = b2f(a0[0]) + b2f(a1[0]);
    sOD[prow][mp+1] = b2f(a0[1]) + b2f(a1[1]);
  }
  __syncthreads();
  int wv2 = tid >> 6, lane = tid & 63;
  int qd = lane >> 4, mr = lane & 15;
  frag_cd acc[4] = {};
  #pragma unroll
  for (int k0=0;k0<128;k0+=32){
    frag_ab af = *reinterpret_cast<frag_ab*>(&sA[wv2*16+mr][k0+qd*8]);
    #pragma unroll
    for (int t=0;t<4;t++){
      frag_ab bfr = ld_frag_2xb64(&sBt[t*16+mr][k0+qd*8]);
      acc[t] = __builtin_amdgcn_mfma_f32_16x16x32_bf16(af, bfr, acc[t], 0, 0, 0);
    }
  }
  #pragma unroll
  for (int r=0;r<4;r++){
    int m = m0 + wv2*16 + qd*4 + r;
    float bias = pwb[m];
    float g = GATE[b*128 + m];
    #pragma unroll
    for (int t=0;t<4;t++){
      float val = acc[t][r] + bias + sOD[t*16+mr][m - m0];
      int p = p0 + t*16 + mr;
      size_t i = ((size_t)b*128 + m)*LLEN + p;
      out[i] = val*g + x[i];
    }
  }
}

extern "C" void kernel_launch(void* const* d_in, const int* in_sizes, int n_in,
                              void* d_out, int out_size, void* d_ws, size_t ws_size,
                              hipStream_t stream) {
  const float* x      = (const float*)d_in[0];
  const float* nhw    = (const float*)d_in[1];
  const float* nhb    = (const float*)d_in[2];
  const float* nvw    = (const float*)d_in[3];
  const float* nvb    = (const float*)d_in[4];
  const float* dww    = (const float*)d_in[5];
  const float* dwb    = (const float*)d_in[6];
  const float* pww    = (const float*)d_in[7];
  const float* pwb    = (const float*)d_in[8];
  const float* h_inw  = (const float*)d_in[9];
  const float* h_cw   = (const float*)d_in[10];
  const float* h_cb   = (const float*)d_in[11];
  const float* h_xw   = (const float*)d_in[12];
  const float* h_dtw  = (const float*)d_in[13];
  const float* h_dtb  = (const float*)d_in[14];
  const float* h_Al   = (const float*)d_in[15];
  const float* h_D    = (const float*)d_in[16];
  const float* h_ow   = (const float*)d_in[17];
  const float* v_inw  = (const float*)d_in[18];
  const float* v_cw   = (const float*)d_in[19];
  const float* v_cb   = (const float*)d_in[20];
  const float* v_xw   = (const float*)d_in[21];
  const float* v_dtw  = (const float*)d_in[22];
  const float* v_dtb  = (const float*)d_in[23];
  const float* v_Al   = (const float*)d_in[24];
  const float* v_D    = (const float*)d_in[25];
  const float* v_ow   = (const float*)d_in[26];
  const float* fc1    = (const float*)d_in[27];
  const float* fc2    = (const float*)d_in[28];

  float* out = (float*)d_out;

  // Staging that is fully consumed BEFORE k_pwcomb's out writes lives in d_out:
  bf16*  WBIN  = (bf16*) ((char*)d_out + 0);        // 262,144 B  [dir][512][128]
  bf16*  WBOUT = (bf16*) ((char*)d_out + 262144);   // 131,072 B  [dir][128][256]
  bf16*  WBX   = (bf16*) ((char*)d_out + 393216);   //  49,152 B  [dir][48][256]
  float* TSUMP = (float*)((char*)d_out + 442368);   //   4,096 B  [4 seg][256 bc]
  float* OSUMP = (float*)((char*)d_out + 446464);   // 200,704 B  [4 bd][98 t][128 m]
                                                    // ends 647,168 << 12.8 MB

  // Workspace layout (bytes). Stream-ordered-safe aliases:
  //  DT2 at base+0 (XLN under it dead after k_inproj); OD overlays DT2 (dead after k_scan3)
  //  YS overlays XI (XI dead after k_dbl); Pbuf/Hbuf outside all aliases
  char* base = (char*)d_ws;
  bf16*  XLN   = (bf16*)(base + 1605632);     // 3,211,264 B
  bf16*  DT2   = (bf16*)(base + 0);           // 6,422,528 B  [overlays XLN region; scan layout]
  bf16*  OD    = (bf16*)(base + 0);           // 3,211,264 B  [alias DT2; live after k_scan3]
  bf16*  XI    = (bf16*)(base + 6422528);     // 6,422,528 B
  bf16*  YS    = (bf16*)(base + 6422528);     // 6,422,528 B  [alias XI]
  bf16*  Z     = (bf16*)(base + 12845056);    // 6,422,528 B
  bf16*  XS2   = (bf16*)(base + 19267584);    // 6,422,528 B  [scan layout]
  float* Bf    = (float*)(base + 25690112);   //   802,816 B
  float* Cf    = (float*)(base + 26492928);   //   802,816 B
  float* Hbuf  = (float*)(base + 27295744);   // 3,211,264 B
  bf16*  TMP   = (bf16*)(base + 30508032);    // 1,605,632 B  (ends 32,113,664)
  float* Pbuf  = (float*)(base + 32113664);   // 3,211,264 B  (ends 35,324,928)
  bf16*  WBPW  = (bf16*) (base + 35326464);   //  32,768 B [128][128] (ends 35,359,232)
  float* GATE  = (float*)(base + 35359232);   //   1,024 B (ends 35,360,256)

  k_front<<<dim3(1024 + 56*BATCH + 64), dim3(256), 0, stream>>>(
      x, dww, dwb, TMP, nhw, nhb, nvw, nvb, XLN,
      h_inw, v_inw, h_ow, v_ow, pww, h_xw, v_xw, WBIN, WBOUT, WBPW, WBX, TSUMP);
  k_inproj<<<dim3(98,4,2), dim3(256), 0, stream>>>(XLN, WBIN, XI, Z);
  k_dbl<<<dim3(392), dim3(256), 0, stream>>>(XI, h_cw, h_cb, v_cw, v_cb,
                                             WBX, h_dtw, v_dtw, h_dtb, v_dtb,
                                             XS2, DT2, Bf, Cf);
  k_scan1<<<dim3(NCHUNK,16,4), dim3(256), 0, stream>>>(DT2, XS2, Bf, h_Al, v_Al, Pbuf, Hbuf);
  k_scan3<<<dim3(NCHUNK,16,4), dim3(256), 0, stream>>>(DT2, XS2, Bf, Cf, h_Al, v_Al,
                                                       Pbuf, Hbuf, YS);
  k_outgemm<<<dim3(196,2), dim3(256), 0, stream>>>(YS, XS2, Z, h_D, v_D, WBOUT, OD, OSUMP);
  k_gate<<<dim3(BATCH), dim3(256), 0, stream>>>(TSUMP, OSUMP, WBPW, pwb, fc1, fc2, GATE);
  k_pwcomb<<<dim3(49,2,BATCH), dim3(256), 0, stream>>>(TMP, WBPW, pwb, OD, x, out, GATE);
}

// Round 11
// 207.889 us; speedup vs baseline: 1.1328x; 1.0169x over previous
//
#include <hip/hip_runtime.h>
#include <hip/hip_bf16.h>

typedef __hip_bfloat16 bf16;
__device__ __forceinline__ float b2f(bf16 v){ return __bfloat162float(v); }
__device__ __forceinline__ bf16 f2b(float v){ return __float2bfloat16(v); }

typedef __attribute__((ext_vector_type(8))) short frag_ab;   // 8 bf16 (4 VGPRs)
typedef __attribute__((ext_vector_type(4))) float frag_cd;   // 4 fp32 acc
typedef __attribute__((ext_vector_type(4))) short short4v;   // 8B

__device__ __forceinline__ frag_ab ld_frag_2xb64(const bf16* p){
  union { frag_ab f; short4v h[2]; } u;
  u.h[0] = *reinterpret_cast<const short4v*>(p);
  u.h[1] = *reinterpret_cast<const short4v*>(p+4);
  return u.f;
}

#define LLEN 3136
#define BATCH 2
#define NCHUNK 49
#define LC 64

// ---- dwconv3x3+gelu + TSUM partial (blk<1024) | LayerNorm (1024..1135) | weight prep (1136..1199) ----
__global__ void k_front(const float* __restrict__ x, const float* __restrict__ dww,
                        const float* __restrict__ dwb, bf16* __restrict__ tmp,
                        const float* nhw_, const float* nhb_, const float* nvw_,
                        const float* nvb_, bf16* __restrict__ xln,
                        const float* __restrict__ h_inw, const float* __restrict__ v_inw,
                        const float* __restrict__ h_ow,  const float* __restrict__ v_ow,
                        const float* __restrict__ pww,   const float* __restrict__ h_xw,
                        const float* __restrict__ v_xw,
                        bf16* __restrict__ WBIN, bf16* __restrict__ WBOUT,
                        bf16* __restrict__ WBPW, bf16* __restrict__ WBX,
                        float* __restrict__ TSUMP){
  int blk = blockIdx.x;
  int tid = threadIdx.x;
  if (blk < 1024){
    int bc = blk & 255;            // b*128 + c
    int seg = blk >> 8;
    int c = bc & 127;
    const float* xp = x + (size_t)bc*LLEN;
    __shared__ float sxr[16][60];  // rows r0-1..r0+14 of this channel, cols zero-padded
    __shared__ float wsum[4];
    int r0 = seg*14;
    for (int idx = tid; idx < 16*56; idx += 256){
      int rr = idx/56, cc = idx%56;
      int gr = r0 - 1 + rr;
      sxr[rr][cc+1] = (gr >= 0 && gr < 56) ? xp[gr*56+cc] : 0.f;
    }
    if (tid < 16){ sxr[tid][0] = 0.f; sxr[tid][57] = 0.f; }
    float w[9];
    #pragma unroll
    for (int i=0;i<9;i++) w[i] = dww[c*9+i];
    float bias = dwb[c];
    __syncthreads();
    int pstart = seg * 784;
    float ts = 0.f;
    for (int p = pstart + tid; p < pstart + 784; p += 256){
      int i = p/56, j = p%56;
      int li = i - r0;
      float acc = bias;
      #pragma unroll
      for (int a=0;a<3;a++)
        #pragma unroll
        for (int bb=0;bb<3;bb++)
          acc += w[a*3+bb] * sxr[li+a][j+bb];
      float g = 0.5f*acc*(1.0f + erff(acc*0.70710678118654752f));
      bf16 gb = f2b(g);
      tmp[(size_t)bc*LLEN + p] = gb;
      ts += b2f(gb);               // bf16-rounded sum (matches what pwcomb's MFMA consumes)
    }
    // block reduce 256 lanes -> 1
    ts += __shfl_xor(ts, 1, 64);
    ts += __shfl_xor(ts, 2, 64);
    ts += __shfl_xor(ts, 4, 64);
    ts += __shfl_xor(ts, 8, 64);
    ts += __shfl_xor(ts, 16, 64);
    ts += __shfl_xor(ts, 32, 64);
    if ((tid & 63) == 0) wsum[tid >> 6] = ts;
    __syncthreads();
    if (tid == 0) TSUMP[seg*256 + bc] = wsum[0]+wsum[1]+wsum[2]+wsum[3];
  } else if (blk < 1136){
    int idx2 = blk - 1024;         // 0..111
    int h = idx2 % 56, b = idx2 / 56;
    __shared__ float sx[128][57];
    __shared__ float smean[56], srstd[56];
    __shared__ float wh[128], bh[128], wv_[128], bv_[128];
    if (tid < 128){ wh[tid]=nhw_[tid]; bh[tid]=nhb_[tid];
                    wv_[tid]=nvw_[tid]; bv_[tid]=nvb_[tid]; }
    for (int idx = tid; idx < 128*56; idx += 256){
      int c = idx / 56, w = idx % 56;
      sx[c][w] = x[((size_t)(b*128+c))*LLEN + h*56 + w];
    }
    __syncthreads();
    if (tid < 56){
      float s=0.f, s2=0.f;
      for (int c=0;c<128;c++){ float v = sx[c][tid]; s+=v; s2+=v*v; }
      float m = s*(1.f/128.f);
      float var = s2*(1.f/128.f) - m*m;
      smean[tid]=m; srstd[tid]=rsqrtf(var+1e-5f);
    }
    __syncthreads();
    bf16* outh = xln;
    bf16* outv = xln + (size_t)BATCH*LLEN*128;
    for (int idx = tid; idx < 56*128; idx += 256){
      int w = idx >> 7, c = idx & 127;
      float v = (sx[c][w]-smean[w])*srstd[w];
      outh[((size_t)b*LLEN + h*56 + w)*128 + c] = f2b(v*wh[c]+bh[c]);
      outv[((size_t)b*LLEN + w*56 + h)*128 + c] = f2b(v*wv_[c]+bv_[c]);
    }
  } else {
    // weight prep: f32 -> bf16 once per launch. Each thread: 16 consecutive elems.
    int pblk = blk - 1136;         // 0..63
    int t16 = tid*16;
    if (pblk < 32){                // WBIN: [dir][512][128], 131072 elems
      int g = pblk*4096 + t16;
      int dir = g >> 16, off = g & 65535;
      const float* src = (dir ? v_inw : h_inw) + off;
      bf16* dst = WBIN + g;
      #pragma unroll
      for (int r=0;r<4;r++){
        float4 w4 = *reinterpret_cast<const float4*>(src + r*4);
        bf16 t4[4] = {f2b(w4.x), f2b(w4.y), f2b(w4.z), f2b(w4.w)};
        *reinterpret_cast<double*>(dst + r*4) = *reinterpret_cast<double*>(t4);
      }
    } else if (pblk < 48){         // WBOUT: [dir][128][256], 65536 elems
      int g = (pblk-32)*4096 + t16;
      int dir = g >> 15, off = g & 32767;
      const float* src = (dir ? v_ow : h_ow) + off;
      bf16* dst = WBOUT + g;
      #pragma unroll
      for (int r=0;r<4;r++){
        float4 w4 = *reinterpret_cast<const float4*>(src + r*4);
        bf16 t4[4] = {f2b(w4.x), f2b(w4.y), f2b(w4.z), f2b(w4.w)};
        *reinterpret_cast<double*>(dst + r*4) = *reinterpret_cast<double*>(t4);
      }
    } else if (pblk < 52){         // WBPW: [128][128], 16384 elems
      int g = (pblk-48)*4096 + t16;
      const float* src = pww + g;
      bf16* dst = WBPW + g;
      #pragma unroll
      for (int r=0;r<4;r++){
        float4 w4 = *reinterpret_cast<const float4*>(src + r*4);
        bf16 t4[4] = {f2b(w4.x), f2b(w4.y), f2b(w4.z), f2b(w4.w)};
        *reinterpret_cast<double*>(dst + r*4) = *reinterpret_cast<double*>(t4);
      }
    } else if (pblk < 58){         // WBX: [dir][48][256], rows>=40 zero, 24576 elems
      int g = (pblk-52)*4096 + t16;
      int dir = (g >= 12288) ? 1 : 0;
      int off = g - dir*12288;
      int rr = off >> 8, cc = off & 255;
      bf16* dst = WBX + g;
      if (rr < 40){
        const float* src = (dir ? v_xw : h_xw) + rr*256 + cc;
        #pragma unroll
        for (int r=0;r<4;r++){
          float4 w4 = *reinterpret_cast<const float4*>(src + r*4);
          bf16 t4[4] = {f2b(w4.x), f2b(w4.y), f2b(w4.z), f2b(w4.w)};
          *reinterpret_cast<double*>(dst + r*4) = *reinterpret_cast<double*>(t4);
        }
      } else {
        bf16 z4[4] = {f2b(0.f), f2b(0.f), f2b(0.f), f2b(0.f)};
        double zd = *reinterpret_cast<double*>(z4);
        #pragma unroll
        for (int r=0;r<4;r++) *reinterpret_cast<double*>(dst + r*4) = zd;
      }
    }
  }
}

// ---------------- in_proj GEMM (MFMA bf16): 64-row tile, 2 n-tiles per block, bf16 weights ----------------
__global__ void k_inproj(const bf16* __restrict__ xln, const bf16* __restrict__ WBIN,
                         bf16* __restrict__ XI, bf16* __restrict__ Z){
  int dir = blockIdx.z;
  const bf16* A = xln + (size_t)dir*BATCH*LLEN*128;
  const bf16* Wb = WBIN + (size_t)dir*512*128;
  int m0 = blockIdx.x*64;
  int npair = blockIdx.y*128;     // covers n0 = npair, npair+64 (same XI/Z half)
  __shared__ __align__(16) bf16 sA[64][136];
  __shared__ __align__(16) bf16 sW[64][136];
  int tid = threadIdx.x;
  #pragma unroll
  for (int r=0;r<4;r++){
    int idx = tid + r*256;
    int row = idx >> 4, c8 = (idx & 15)*8;
    *reinterpret_cast<float4*>(&sA[row][c8]) =
        *reinterpret_cast<const float4*>(&A[(size_t)(m0+row)*128 + c8]);
  }
  int wv2 = tid >> 6, lane = tid & 63;
  int qd = lane >> 4, mr = lane & 15;
  bf16* dst = (npair < 256) ? XI : Z;
  int nbase0 = npair & 255;
  size_t dslab = (size_t)dir*BATCH*LLEN*256;
  #pragma unroll
  for (int nt=0; nt<2; nt++){
    int n0 = npair + nt*64;
    __syncthreads();
    #pragma unroll
    for (int r=0;r<4;r++){
      int idx = tid + r*256;
      int row = idx >> 4, c8 = (idx & 15)*8;
      *reinterpret_cast<float4*>(&sW[row][c8]) =
          *reinterpret_cast<const float4*>(&Wb[(size_t)(n0+row)*128 + c8]);
    }
    __syncthreads();
    frag_cd acc[4] = {};
    #pragma unroll
    for (int k0=0;k0<128;k0+=32){
      frag_ab af = *reinterpret_cast<frag_ab*>(&sA[wv2*16+mr][k0+qd*8]);
      #pragma unroll
      for (int t=0;t<4;t++){
        frag_ab bfr = *reinterpret_cast<frag_ab*>(&sW[t*16+mr][k0+qd*8]);
        acc[t] = __builtin_amdgcn_mfma_f32_16x16x32_bf16(af, bfr, acc[t], 0, 0, 0);
      }
    }
    int nb = nbase0 + nt*64;
    #pragma unroll
    for (int t=0;t<4;t++)
      #pragma unroll
      for (int r=0;r<4;r++){
        int row = m0 + wv2*16 + qd*4 + r;
        int col = nb + t*16 + mr;
        dst[dslab + (size_t)row*256 + col] = f2b(acc[t][r]);
      }
  }
}

// ---- fused conv1d(k=4,causal)+silu + xproj (MFMA): 32-row tiles, 392 blocks (own-halo) ----
__global__ void k_dbl(const bf16* __restrict__ XI,
                      const float* hcw, const float* hcb, const float* vcw, const float* vcb,
                      const bf16* __restrict__ WBX,
                      const float* hdw, const float* vdw, const float* hdb, const float* vdb,
                      bf16* __restrict__ XS2, bf16* __restrict__ DT2,
                      float* __restrict__ Bf, float* __restrict__ Cf){
  int m0 = blockIdx.x*32;                      // 392 tiles; 3136 % 32 == 0, never crosses bd
  int bd = m0 / LLEN;
  int l0m = m0 % LLEN;
  int dirq = bd >> 1;
  const bf16* XId = XI + (size_t)bd*LLEN*256;
  const bf16* Wb = WBX + (size_t)dirq*48*256;
  const float* cw = dirq ? vcw : hcw;
  const float* cb = dirq ? vcb : hcb;
  __shared__ __align__(16) bf16 sA[35][264];   // rows = XI[l0m-3 .. l0m+31]; conv overwrites rows 0..31
  __shared__ __align__(16) bf16 sW[48][264];   // rows 40..47 zero (prepped)
  __shared__ float sdbl[32][49];
  int tid = threadIdx.x;
  for (int idx = tid; idx < 35*32; idx += 256){
    int row = idx >> 5, c8 = (idx & 31)*8;
    int l = l0m - 3 + row;
    float4 v = make_float4(0.f,0.f,0.f,0.f);
    if (l >= 0) v = *reinterpret_cast<const float4*>(&XId[(size_t)l*256 + c8]);
    *reinterpret_cast<float4*>(&sA[row][c8]) = v;
  }
  #pragma unroll
  for (int r=0;r<6;r++){
    int idx = tid + r*256;                     // 1536 = 48*32 chunks of 8
    int row = idx >> 5, c8 = (idx & 31)*8;
    *reinterpret_cast<float4*>(&sW[row][c8]) =
        *reinterpret_cast<const float4*>(&Wb[(size_t)row*256 + c8]);
  }
  __syncthreads();
  {
    float w0=cw[tid*4], w1=cw[tid*4+1], w2=cw[tid*4+2], w3=cw[tid*4+3];
    float cbias = cb[tid];
    size_t x2base = ((size_t)bd*16 + (tid>>4))*LLEN + l0m;
    int c16 = tid & 15;
    float xm3 = b2f(sA[0][tid]), xm2 = b2f(sA[1][tid]), xm1 = b2f(sA[2][tid]);
    #pragma unroll 4
    for (int j=0;j<32;j++){
      float x0 = b2f(sA[j+3][tid]);
      float acc = cbias + w0*xm3 + w1*xm2 + w2*xm1 + w3*x0;
      float s = acc / (1.f + __expf(-acc));
      bf16 sv = f2b(s);
      sA[j][tid] = sv;                         // row j no longer read (window advanced)
      XS2[(x2base + j)*16 + c16] = sv;
      xm3=xm2; xm2=xm1; xm1=x0;
    }
  }
  __syncthreads();
  int wv2 = tid >> 6, lane = tid & 63;
  int qd = lane >> 4, mr = lane & 15;
  if (wv2 < 2){                                // 2 m-subtiles of 16 rows; waves 0-1 compute
    frag_cd acc[3] = {};
    #pragma unroll
    for (int k0=0;k0<256;k0+=32){
      frag_ab af = *reinterpret_cast<frag_ab*>(&sA[wv2*16+mr][k0+qd*8]);
      #pragma unroll
      for (int t=0;t<3;t++){
        frag_ab bfr = *reinterpret_cast<frag_ab*>(&sW[t*16+mr][k0+qd*8]);
        acc[t] = __builtin_amdgcn_mfma_f32_16x16x32_bf16(af, bfr, acc[t], 0, 0, 0);
      }
    }
    #pragma unroll
    for (int t=0;t<3;t++)
      #pragma unroll
      for (int r=0;r<4;r++){
        int col = t*16 + mr;
        if (col < 40) sdbl[wv2*16 + qd*4 + r][col] = acc[t][r];
      }
  }
  __syncthreads();
  const float* dtw = dirq ? vdw : hdw;
  const float* dtb = dirq ? vdb : hdb;
  float w8[8];
  #pragma unroll
  for (int r=0;r<8;r++) w8[r] = dtw[tid*8+r];
  float biasv = dtb[tid];
  size_t d2base = ((size_t)bd*16 + (tid>>4))*LLEN + l0m;
  int c16 = tid & 15;
  for (int row=0; row<32; row++){
    float a = biasv;
    #pragma unroll
    for (int r=0;r<8;r++) a += sdbl[row][r]*w8[r];
    float sv = (a > 20.f) ? a : __logf(1.f + __expf(a));
    DT2[(d2base + row)*16 + c16] = f2b(sv);
  }
  #pragma unroll
  for (int r=0;r<4;r++){
    int idx = tid + r*256;                     // 1024 = 32 rows * 32 vals
    int row = idx >> 5, o = idx & 31;
    float v = sdbl[row][8+o];
    size_t rr = (size_t)(m0+row)*16;
    if (o < 16) Bf[rr + o] = v;
    else        Cf[rr + (o-16)] = v;
  }
}

// ---------------- scan pass 1: local chunk scan (plain stores, no cross-block sync) ----------------
__global__ void k_scan1(const bf16* __restrict__ DT2, const bf16* __restrict__ XS2,
                        const float* __restrict__ Bc, const float* hA, const float* vA,
                        float* __restrict__ Pbuf, float* __restrict__ Hbuf){
  int bd = blockIdx.z;           // dir*2+b
  int g  = blockIdx.y;           // channel group 0..15
  int ck = blockIdx.x;           // chunk 0..48
  int l0 = ck*LC;
  const float* Bd = Bc + (size_t)bd*LLEN*16;
  const float* Alog = (bd >> 1) ? vA : hA;
  int tid = threadIdx.x;
  int dl = tid >> 4, n = tid & 15;
  float A = -__expf(Alog[(g*16+dl)*16+n]);
  __shared__ float sdt[LC][16], sxs[LC][16], sB[LC][16];
  size_t base2 = (((size_t)bd*16 + g)*LLEN + l0)*16;
  #pragma unroll
  for (int r=0;r<4;r++){
    int idx = tid + r*256;
    sdt[idx>>4][idx&15] = b2f(DT2[base2 + idx]);
    sxs[idx>>4][idx&15] = b2f(XS2[base2 + idx]);
    (&sB[0][0])[idx] = Bd[(size_t)l0*16 + idx];
  }
  __syncthreads();
  float h = 0.f, P = 1.f;
  #pragma unroll 8
  for (int i=0;i<LC;i++){
    float a = sdt[i][dl];
    float u = sxs[i][dl];
    float dA = __expf(a * A);
    h = dA*h + (a*u)*sB[i][n];
    P *= dA;
  }
  size_t sidx = (((size_t)bd*16 + g)*NCHUNK + ck)*256 + tid;
  Pbuf[sidx] = P;
  Hbuf[sidx] = h;
}

// ------- pass 3: redundant per-block prefix combine (scan2 fused) + local scan + LDS reduce -------
__global__ void k_scan3(const bf16* __restrict__ DT2, const bf16* __restrict__ XS2,
                        const float* __restrict__ Bc, const float* __restrict__ Cc,
                        const float* hA, const float* vA,
                        const float* __restrict__ Pbuf, const float* __restrict__ Hbuf,
                        bf16* __restrict__ ys){
  int bd = blockIdx.z;
  int g  = blockIdx.y;
  int ck = blockIdx.x;
  int l0 = ck*LC;
  const float* Bd = Bc + (size_t)bd*LLEN*16;
  const float* Cd = Cc + (size_t)bd*LLEN*16;
  bf16* yd = ys + (size_t)bd*LLEN*256;
  const float* Alog = (bd >> 1) ? vA : hA;
  int tid = threadIdx.x;
  int dl = tid >> 4, n = tid & 15;
  float A = -__expf(Alog[(g*16+dl)*16+n]);
  __shared__ float sdt[LC][16], sxs[LC][16], sB[LC][16], sC[LC][16];
  __shared__ float sp2[16][272];   // swizzled: element (dl,n) at dl*17+n -> <=2-way banks
  size_t base2 = (((size_t)bd*16 + g)*LLEN + l0)*16;
  #pragma unroll
  for (int r=0;r<4;r++){
    int idx = tid + r*256;
    sdt[idx>>4][idx&15] = b2f(DT2[base2 + idx]);
    sxs[idx>>4][idx&15] = b2f(XS2[base2 + idx]);
    (&sB[0][0])[idx] = Bd[(size_t)l0*16 + idx];
    (&sC[0][0])[idx] = Cd[(size_t)l0*16 + idx];
  }
  // prefix combine over chunks 0..ck-1 (same order as the old scan2; batched-8 for MLP)
  float h = 0.f;
  {
    size_t qbase = (size_t)(bd*16 + g)*NCHUNK*256 + tid;
    int k = 0;
    for (; k+8 <= ck; k += 8){
      float Pv[8], Hv[8];
      #pragma unroll
      for (int j=0;j<8;j++){
        Pv[j] = Pbuf[qbase + (size_t)(k+j)*256];
        Hv[j] = Hbuf[qbase + (size_t)(k+j)*256];
      }
      #pragma unroll
      for (int j=0;j<8;j++) h = Pv[j]*h + Hv[j];
    }
    for (; k < ck; ++k)
      h = Pbuf[qbase + (size_t)k*256]*h + Hbuf[qbase + (size_t)k*256];
  }
  __syncthreads();
  int swz = dl*17 + n;
  int i_local = tid >> 4;
  int c16 = tid & 15;
  int rbase = c16*17;
  for (int i0=0; i0<LC; i0+=16){
    #pragma unroll
    for (int ii=0;ii<16;ii++){
      int i = i0 + ii;
      float a = sdt[i][dl];
      float u = sxs[i][dl];
      float dA = __expf(a * A);
      h = dA*h + (a*u)*sB[i][n];
      sp2[ii][swz] = h * sC[i][n];
    }
    __syncthreads();
    const float* row = &sp2[i_local][rbase];
    float s = 0.f;
    #pragma unroll
    for (int k=0;k<16;k++) s += row[k];
    yd[(size_t)(l0+i0+i_local)*256 + g*16 + c16] = f2b(s);
    __syncthreads();
  }
}

// ---- out_proj GEMM: 32-row tiles, both n-halves, bf16 weights; emits transposed OD column sums ----
__global__ void k_outgemm(const bf16* __restrict__ ys, const bf16* __restrict__ XS2,
                          const bf16* __restrict__ Z, const float* __restrict__ hD,
                          const float* __restrict__ vD, const bf16* __restrict__ WBOUT,
                          bf16* __restrict__ OD, float* __restrict__ OSUMP){
  int dir = blockIdx.y;
  size_t slab = (size_t)dir*BATCH*LLEN*256;
  const bf16* Wb = WBOUT + (size_t)dir*128*256;
  const float* Dw = dir ? vD : hD;
  bf16* od = OD + (size_t)dir*BATCH*LLEN*128;
  int m0 = blockIdx.x*32;
  int bd = dir*2 + m0/LLEN;
  int lbase = m0 % LLEN;
  __shared__ __align__(16) bf16 sA[32][264];
  __shared__ __align__(16) bf16 sW[64][264];
  __shared__ float scol[128];
  int tid = threadIdx.x;
  if (tid < 128) scol[tid] = 0.f;
  #pragma unroll
  for (int r=0;r<4;r++){
    int idx = tid + r*256;
    int row = idx >> 5, c8 = (idx & 31)*8;
    size_t e = slab + (size_t)(m0+row)*256 + c8;
    size_t e2 = (((size_t)bd*16 + (c8>>4))*LLEN + lbase + row)*16 + (c8&15);
    bf16 yb[8], xb[8], zb[8], ob[8];
    *reinterpret_cast<float4*>(yb) = *reinterpret_cast<const float4*>(&ys[e]);
    *reinterpret_cast<float4*>(xb) = *reinterpret_cast<const float4*>(&XS2[e2]);
    *reinterpret_cast<float4*>(zb) = *reinterpret_cast<const float4*>(&Z[e]);
    #pragma unroll
    for (int j=0;j<8;j++){
      float Dv = Dw[c8 + j];
      float yv = b2f(yb[j]) + b2f(xb[j])*Dv;
      float zv = b2f(zb[j]);
      ob[j] = f2b(yv * (zv/(1.f+__expf(-zv))));
    }
    *reinterpret_cast<float4*>(&sA[row][c8]) = *reinterpret_cast<float4*>(ob);
  }
  int wv2 = tid >> 6, lane = tid & 63;
  int qd = lane >> 4, mr = lane & 15;
  int msub = wv2 & 1, tpair = (wv2 >> 1)*2;
  #pragma unroll
  for (int nh=0; nh<2; nh++){
    int n0 = nh*64;
    __syncthreads();
    #pragma unroll
    for (int r=0;r<8;r++){
      int idx = tid + r*256;
      int row = idx >> 5, c8 = (idx & 31)*8;
      *reinterpret_cast<float4*>(&sW[row][c8]) =
          *reinterpret_cast<const float4*>(&Wb[(size_t)(n0+row)*256 + c8]);
    }
    __syncthreads();
    frag_cd acc[2] = {};
    #pragma unroll
    for (int k0=0;k0<256;k0+=32){
      frag_ab af = *reinterpret_cast<frag_ab*>(&sA[msub*16+mr][k0+qd*8]);
      #pragma unroll
      for (int i=0;i<2;i++){
        frag_ab bfr = *reinterpret_cast<frag_ab*>(&sW[(tpair+i)*16+mr][k0+qd*8]);
        acc[i] = __builtin_amdgcn_mfma_f32_16x16x32_bf16(af, bfr, acc[i], 0, 0, 0);
      }
    }
    #pragma unroll
    for (int i=0;i<2;i++){
      float cs = 0.f;
      #pragma unroll
      for (int r=0;r<4;r++){
        int row = m0 + msub*16 + qd*4 + r;
        int col = n0 + (tpair+i)*16 + mr;
        bf16 ov = f2b(acc[i][r]);
        od[(size_t)row*128 + col] = ov;
        cs += b2f(ov);                 // bf16-rounded (matches pwcomb's sOD consumption)
      }
      cs += __shfl_xor(cs, 16, 64);    // reduce over qd
      cs += __shfl_xor(cs, 32, 64);
      if (qd == 0) atomicAdd(&scol[n0 + (tpair+i)*16 + mr], cs);   // LDS atomic
    }
  }
  __syncthreads();
  if (tid < 128){
    int b = m0 / LLEN;
    int t = blockIdx.x % 98;
    // transposed: [b][m][dir*98 + t] -> pwcomb reads 196 contiguous floats per m
    OSUMP[((size_t)(b*128 + tid))*196 + dir*98 + t] = scol[tid];
  }
}

// ---- pw conv (MFMA) + combine + redundant in-block gate + final out; NO cross-block sync ----
__global__ void k_pwcomb(const bf16* __restrict__ tmp, const bf16* __restrict__ WBPW,
                         const float* __restrict__ pwb, const bf16* __restrict__ OD,
                         const float* __restrict__ x, float* __restrict__ out,
                         const float* __restrict__ TSUMP, const float* __restrict__ OSUMP,
                         const float* __restrict__ fc1, const float* __restrict__ fc2){
  int p0 = blockIdx.x * 64;       // 49 p-tiles
  int m0 = blockIdx.y * 64;       // 2 out-channel halves
  int b  = blockIdx.z;
  const bf16* T = tmp + (size_t)b*128*LLEN;
  const bf16* od0 = OD + (size_t)b*LLEN*128;
  const bf16* od1 = OD + (size_t)(BATCH + b)*LLEN*128;
  __shared__ __align__(16) bf16 sA[64][136];    // pww rows m0.., k=c (bf16)
  __shared__ __align__(16) bf16 sBt[64][132];   // [p][c] transposed tmp tile
  __shared__ float sOD[64][65];                 // [p][m] od0 + od1^T
  __shared__ float tsh[128], ym[128], s1g[32], gsh[128];
  int tid = threadIdx.x;
  #pragma unroll
  for (int r=0;r<4;r++){
    int idx = tid + r*256;
    int row = idx >> 4, c8 = (idx & 15)*8;
    *reinterpret_cast<float4*>(&sA[row][c8]) =
        *reinterpret_cast<const float4*>(&WBPW[(size_t)(m0+row)*128 + c8]);
  }
  #pragma unroll
  for (int r=0;r<8;r++){
    int idx = tid + r*256;
    int c = idx >> 4, p4 = (idx & 15)*4;
    union { double d; bf16 v[4]; } u;
    u.d = *reinterpret_cast<const double*>(&T[(size_t)c*LLEN + p0 + p4]);
    #pragma unroll
    for (int j=0;j<4;j++) sBt[p4+j][c] = u.v[j];
  }
  #pragma unroll
  for (int r=0;r<8;r++){
    int idx = tid + r*256;       // 2048 = 64 p-rows * 32 m-pairs
    int prow = idx >> 5, mp = (idx & 31)*2;
    int p = p0 + prow;
    int pi = p/56, pj = p%56;
    int pt = pj*56 + pi;
    bf16 a0[2], a1[2];
    *reinterpret_cast<float*>(a0) = *reinterpret_cast<const float*>(&od0[(size_t)p*128 + m0 + mp]);
    *reinterpret_cast<float*>(a1) = *reinterpret_cast<const float*>(&od1[(size_t)pt*128 + m0 + mp]);
    sOD[prow][mp]   = b2f(a0[0]) + b2f(a1[0]);
    sOD[prow][mp+1] = b2f(a0[1]) + b2f(a1[1]);
  }
  if (tid < 128)
    tsh[tid] = TSUMP[0*256 + b*128 + tid] + TSUMP[1*256 + b*128 + tid]
             + TSUMP[2*256 + b*128 + tid] + TSUMP[3*256 + b*128 + tid];
  __syncthreads();
  int wv2 = tid >> 6, lane = tid & 63;
  int qd = lane >> 4, mr = lane & 15;
  frag_cd acc[4] = {};
  #pragma unroll
  for (int k0=0;k0<128;k0+=32){
    frag_ab af = *reinterpret_cast<frag_ab*>(&sA[wv2*16+mr][k0+qd*8]);
    #pragma unroll
    for (int t=0;t<4;t++){
      frag_ab bfr = ld_frag_2xb64(&sBt[t*16+mr][k0+qd*8]);
      acc[t] = __builtin_amdgcn_mfma_f32_16x16x32_bf16(af, bfr, acc[t], 0, 0, 0);
    }
  }
  // redundant in-block gate: ym = (pww@tsum + osum)/LLEN + pwb, then the MLP (same order as old k_gate)
  if (tid < 128){
    float os = 0.f;
    const float* orow = &OSUMP[(size_t)(b*128 + tid)*196];
    #pragma unroll 7
    for (int j=0;j<49;j++){
      float4 v = *reinterpret_cast<const float4*>(&orow[j*4]);
      os += v.x; os += v.y; os += v.z; os += v.w;
    }
    float pwpart = 0.f;
    #pragma unroll 8
    for (int c=0; c<128; c++)
      pwpart += b2f(WBPW[tid*128 + c]) * tsh[c];
    ym[tid] = (pwpart + os)*(1.f/(float)LLEN) + pwb[tid];
  }
  __syncthreads();
  {
    int o = tid >> 3, part = tid & 7;   // 32 outputs x 8 partials
    float a = 0.f;
    #pragma unroll
    for (int k=0;k<16;k++) a += ym[part*16 + k] * fc1[o*128 + part*16 + k];
    a += __shfl_xor(a, 1, 8);
    a += __shfl_xor(a, 2, 8);
    a += __shfl_xor(a, 4, 8);
    if (part == 0) s1g[o] = fmaxf(a, 0.f);
  }
  __syncthreads();
  if (tid < 128){
    float a = 0.f;
    #pragma unroll
    for (int j=0;j<32;j++) a += s1g[j]*fc2[tid*32+j];
    gsh[tid] = 1.f/(1.f+__expf(-a));
  }
  __syncthreads();
  #pragma unroll
  for (int r=0;r<4;r++){
    int m = m0 + wv2*16 + qd*4 + r;
    float bias = pwb[m];
    float g = gsh[m & 127];
    #pragma unroll
    for (int t=0;t<4;t++){
      float val = acc[t][r] + bias + sOD[t*16+mr][m - m0];
      int p = p0 + t*16 + mr;
      size_t i = ((size_t)b*128 + m)*LLEN + p;
      out[i] = val*g + x[i];
    }
  }
}

extern "C" void kernel_launch(void* const* d_in, const int* in_sizes, int n_in,
                              void* d_out, int out_size, void* d_ws, size_t ws_size,
                              hipStream_t stream) {
  const float* x      = (const float*)d_in[0];
  const float* nhw    = (const float*)d_in[1];
  const float* nhb    = (const float*)d_in[2];
  const float* nvw    = (const float*)d_in[3];
  const float* nvb    = (const float*)d_in[4];
  const float* dww    = (const float*)d_in[5];
  const float* dwb    = (const float*)d_in[6];
  const float* pww    = (const float*)d_in[7];
  const float* pwb    = (const float*)d_in[8];
  const float* h_inw  = (const float*)d_in[9];
  const float* h_cw   = (const float*)d_in[10];
  const float* h_cb   = (const float*)d_in[11];
  const float* h_xw   = (const float*)d_in[12];
  const float* h_dtw  = (const float*)d_in[13];
  const float* h_dtb  = (const float*)d_in[14];
  const float* h_Al   = (const float*)d_in[15];
  const float* h_D    = (const float*)d_in[16];
  const float* h_ow   = (const float*)d_in[17];
  const float* v_inw  = (const float*)d_in[18];
  const float* v_cw   = (const float*)d_in[19];
  const float* v_cb   = (const float*)d_in[20];
  const float* v_xw   = (const float*)d_in[21];
  const float* v_dtw  = (const float*)d_in[22];
  const float* v_dtb  = (const float*)d_in[23];
  const float* v_Al   = (const float*)d_in[24];
  const float* v_D    = (const float*)d_in[25];
  const float* v_ow   = (const float*)d_in[26];
  const float* fc1    = (const float*)d_in[27];
  const float* fc2    = (const float*)d_in[28];

  float* out = (float*)d_out;

  // Staging that is fully consumed BEFORE k_pwcomb's out writes lives in d_out:
  bf16*  WBIN  = (bf16*) ((char*)d_out + 0);        // 262,144 B  [dir][512][128]
  bf16*  WBOUT = (bf16*) ((char*)d_out + 262144);   // 131,072 B  [dir][128][256]
  bf16*  WBX   = (bf16*) ((char*)d_out + 393216);   //  49,152 B  [dir][48][256]
  float* TSUMP = (float*)((char*)d_out + 442368);   //   4,096 B  [4 seg][256 bc]
  float* OSUMP = (float*)((char*)d_out + 446464);   // 200,704 B  [2 b][128 m][196]
                                                    // ends 647,168 << 12.8 MB
  // NOTE: TSUMP/OSUMP are read by k_pwcomb BEFORE it writes out; since every pwcomb
  // block reads them at the start and writes `out` only at the end, and they occupy
  // bytes whose final values are produced by those same end-writes, aliasing is safe
  // only if no pwcomb block overwrites them before another reads. To be safe they sit
  // in the FIRST 648 KB of out, which pwcomb blocks (p0,m0,b) write as
  // out[(b*128+m)*3136+p]*4B — the lowest-addressed write is b=0,m=0,p=0 → byte 0.
  // So keep TSUMP/OSUMP consumption strictly before any out write WITHIN each block
  // (true: gate is computed before the epilogue) and accept cross-block risk only if
  // another block's epilogue could land first. To eliminate that risk entirely,
  // TSUMP/OSUMP actually live in the WORKSPACE tail below (pointers overridden).

  // Workspace layout (bytes). Stream-ordered-safe aliases:
  //  DT2 at base+0 (XLN under it dead after k_inproj); OD overlays DT2 (dead after k_scan3)
  //  YS overlays XI (XI dead after k_dbl); Pbuf/Hbuf outside all aliases
  char* base = (char*)d_ws;
  bf16*  XLN   = (bf16*)(base + 1605632);     // 3,211,264 B
  bf16*  DT2   = (bf16*)(base + 0);           // 6,422,528 B  [overlays XLN region; scan layout]
  bf16*  OD    = (bf16*)(base + 0);           // 3,211,264 B  [alias DT2; live after k_scan3]
  bf16*  XI    = (bf16*)(base + 6422528);     // 6,422,528 B
  bf16*  YS    = (bf16*)(base + 6422528);     // 6,422,528 B  [alias XI]
  bf16*  Z     = (bf16*)(base + 12845056);    // 6,422,528 B
  bf16*  XS2   = (bf16*)(base + 19267584);    // 6,422,528 B  [scan layout]
  float* Bf    = (float*)(base + 25690112);   //   802,816 B
  float* Cf    = (float*)(base + 26492928);   //   802,816 B
  float* Hbuf  = (float*)(base + 27295744);   // 3,211,264 B
  bf16*  TMP   = (bf16*)(base + 30508032);    // 1,605,632 B  (ends 32,113,664)
  float* Pbuf  = (float*)(base + 32113664);   // 3,211,264 B  (ends 35,324,928)
  bf16*  WBPW  = (bf16*) (base + 35326464);   //  32,768 B [128][128] (ends 35,359,232)
  TSUMP        = (float*)(base + 35359232);   //   4,096 B (ends 35,363,328)
  OSUMP        = (float*)(base + 35363328);   // 200,704 B (ends 35,564,032)

  k_front<<<dim3(1024 + 56*BATCH + 64), dim3(256), 0, stream>>>(
      x, dww, dwb, TMP, nhw, nhb, nvw, nvb, XLN,
      h_inw, v_inw, h_ow, v_ow, pww, h_xw, v_xw, WBIN, WBOUT, WBPW, WBX, TSUMP);
  k_inproj<<<dim3(98,4,2), dim3(256), 0, stream>>>(XLN, WBIN, XI, Z);
  k_dbl<<<dim3(392), dim3(256), 0, stream>>>(XI, h_cw, h_cb, v_cw, v_cb,
                                             WBX, h_dtw, v_dtw, h_dtb, v_dtb,
                                             XS2, DT2, Bf, Cf);
  k_scan1<<<dim3(NCHUNK,16,4), dim3(256), 0, stream>>>(DT2, XS2, Bf, h_Al, v_Al, Pbuf, Hbuf);
  k_scan3<<<dim3(NCHUNK,16,4), dim3(256), 0, stream>>>(DT2, XS2, Bf, Cf, h_Al, v_Al,
                                                       Pbuf, Hbuf, YS);
  k_outgemm<<<dim3(196,2), dim3(256), 0, stream>>>(YS, XS2, Z, h_D, v_D, WBOUT, OD, OSUMP);
  k_pwcomb<<<dim3(49,2,BATCH), dim3(256), 0, stream>>>(TMP, WBPW, pwb, OD, x, out,
                                                       TSUMP, OSUMP, fc1, fc2);
}